// Round 7
// baseline (262.274 us; speedup 1.0000x reference)
//
#include <hip/hip_runtime.h>

#define NNODES 20000
#define NEDGES 320000
#define SCAN_NB ((NNODES + 255) / 256)   // 79

typedef __attribute__((ext_vector_type(8))) short bf16x8;
typedef __attribute__((ext_vector_type(4))) float f32x4;
typedef _Float16 f16x4 __attribute__((ext_vector_type(4)));

__device__ __forceinline__ float leaky(float x) { return x > 0.f ? x : 0.2f * x; }
__device__ __forceinline__ float elu(float x) { return x > 0.f ? x : expm1f(x); }

__device__ __forceinline__ ushort f2bf(float f) {
  uint u = __float_as_uint(f);
  uint r = (u + 0x7fffu + ((u >> 16) & 1u)) >> 16;
  return (ushort)r;
}
__device__ __forceinline__ float bf2f(ushort h) {
  return __uint_as_float(((uint)h) << 16);
}

// ---------------- CSR build ----------------
__global__ void k_zero(int* __restrict__ p, int n) {
  int i = blockIdx.x * blockDim.x + threadIdx.x;
  if (i < n) p[i] = 0;
}

__global__ void k_hist(const int* __restrict__ dst, int* __restrict__ cnt, int e) {
  int i = blockIdx.x * blockDim.x + threadIdx.x;
  if (i < e) atomicAdd(&cnt[dst[i]], 1);
}

__global__ __launch_bounds__(256) void k_scan1(const int* __restrict__ cnt, int* __restrict__ row_start,
                                               int* __restrict__ blocksum, int n) {
  __shared__ int s[256];
  int t = threadIdx.x;
  int i = blockIdx.x * 256 + t;
  int v = (i < n) ? cnt[i] : 0;
  s[t] = v;
  __syncthreads();
  for (int off = 1; off < 256; off <<= 1) {
    int x = (t >= off) ? s[t - off] : 0;
    __syncthreads();
    s[t] += x;
    __syncthreads();
  }
  if (i < n) row_start[i] = s[t] - v;
  if (t == 255) blocksum[blockIdx.x] = s[255];
}

__global__ __launch_bounds__(128) void k_scan2(int* __restrict__ blocksum, int* __restrict__ blockoff,
                                               int* __restrict__ row_start, int nb, int n) {
  __shared__ int s[128];
  int t = threadIdx.x;
  int v = (t < nb) ? blocksum[t] : 0;
  s[t] = v;
  __syncthreads();
  for (int off = 1; off < 128; off <<= 1) {
    int x = (t >= off) ? s[t - off] : 0;
    __syncthreads();
    s[t] += x;
    __syncthreads();
  }
  if (t < nb) blockoff[t] = s[t] - v;
  if (t == nb - 1) row_start[n] = s[t];
}

__global__ __launch_bounds__(256) void k_scan3(int* __restrict__ row_start, const int* __restrict__ blockoff,
                                               int* __restrict__ fill, int n) {
  int i = blockIdx.x * 256 + threadIdx.x;
  if (i < n) {
    row_start[i] += blockoff[blockIdx.x];
    fill[i] = 0;
  }
}

__global__ void k_scatter(const int* __restrict__ src, const int* __restrict__ dst,
                          const int* __restrict__ row_start, int* __restrict__ fill,
                          int* __restrict__ csr, int e) {
  int i = blockIdx.x * blockDim.x + threadIdx.x;
  if (i < e) {
    int d = dst[i];
    int p = row_start[d] + atomicAdd(&fill[d], 1);
    csr[p] = src[i];
  }
}

// ---------------- fp32 -> packed hi/lo bf16 (MFMA fragment order) ----------------
__global__ void k_cvt_pack(const float* __restrict__ a, ushort* __restrict__ hi,
                           ushort* __restrict__ lo, int total) {
  int i = blockIdx.x * blockDim.x + threadIdx.x;
  if (i >= total) return;
  const float* src = a + (size_t)i * 32;
  ushort h[32], lw[32];
#pragma unroll
  for (int r = 0; r < 32; r++) {
    int p = (r < 16) ? ((r >> 2) * 8 + (r & 3)) : (((r - 16) >> 2) * 8 + 4 + (r & 3));
    float v = src[r];
    ushort hh = f2bf(v);
    h[p] = hh;
    lw[p] = f2bf(v - bf2f(hh));
  }
  ushort* ho = hi + (size_t)i * 32;
  ushort* llo = lo + (size_t)i * 32;
#pragma unroll
  for (int q = 0; q < 4; q++) {
    *(bf16x8*)&ho[q * 8] = *(bf16x8*)&h[q * 8];
    *(bf16x8*)&llo[q * 8] = *(bf16x8*)&lw[q * 8];
  }
}

__global__ void k_prep_w(const float* __restrict__ w, ushort* __restrict__ th,
                         ushort* __restrict__ tl, int K, int OC) {
  int i = blockIdx.x * blockDim.x + threadIdx.x;
  int KC = K / 32;
  if (i >= OC * KC) return;
  int oc = i / KC, c = i % KC;
  ushort h[32], lw[32];
#pragma unroll
  for (int r = 0; r < 32; r++) {
    int p = (r < 16) ? ((r >> 2) * 8 + (r & 3)) : (((r - 16) >> 2) * 8 + 4 + (r & 3));
    float v = w[(size_t)(c * 32 + r) * OC + oc];
    ushort hh = f2bf(v);
    h[p] = hh;
    lw[p] = f2bf(v - bf2f(hh));
  }
  ushort* ho = th + (size_t)oc * K + c * 32;
  ushort* llo = tl + (size_t)oc * K + c * 32;
#pragma unroll
  for (int q = 0; q < 4; q++) {
    *(bf16x8*)&ho[q * 8] = *(bf16x8*)&h[q * 8];
    *(bf16x8*)&llo[q * 8] = *(bf16x8*)&lw[q * 8];
  }
}

// ---------------- MFMA GEMM, register double-buffered, fused asd epilogue -------
// Block: 4 waves, tile = BM(=RT*16) rows x (4*NCT*16) cols, grid.y splits columns.
// Per K-chunk, each wave loads its fragments as one batch into named buffer set
// cur/nxt (no runtime-indexed arrays) so all loads of a chunk are in flight
// while previous chunk's MFMAs execute.
#define LOADC(c, bh, bl, ah, al)                                          \
  {                                                                       \
    _Pragma("unroll") for (int t = 0; t < NCT; t++) {                     \
      int col = cw + 16 * t + lr;                                         \
      bh[t] = *(const bf16x8*)(Bh + (size_t)col * K + (c) * 32 + g8);     \
      bl[t] = *(const bf16x8*)(Bl + (size_t)col * K + (c) * 32 + g8);     \
    }                                                                     \
    _Pragma("unroll") for (int r = 0; r < RT; r++) {                      \
      ah[r] = *(const bf16x8*)(Ah + (size_t)rows[r] * K + (c) * 32 + g8); \
      al[r] = *(const bf16x8*)(Al + (size_t)rows[r] * K + (c) * 32 + g8); \
    }                                                                     \
  }
#define MFMAC(bh, bl, ah, al)                                                      \
  {                                                                                \
    _Pragma("unroll") for (int r = 0; r < RT; r++)                                 \
      _Pragma("unroll") for (int t = 0; t < NCT; t++) {                            \
        acc[r][t] = __builtin_amdgcn_mfma_f32_16x16x32_bf16(ah[r], bh[t], acc[r][t], 0, 0, 0); \
        acc[r][t] = __builtin_amdgcn_mfma_f32_16x16x32_bf16(al[r], bh[t], acc[r][t], 0, 0, 0); \
        acc[r][t] = __builtin_amdgcn_mfma_f32_16x16x32_bf16(ah[r], bl[t], acc[r][t], 0, 0, 0); \
      }                                                                            \
  }

template <int K, int NCT, int HEADS, int RT>
__global__ __launch_bounds__(256) void k_gemm_mfma(const ushort* __restrict__ Ah, const ushort* __restrict__ Al,
                                                   const ushort* __restrict__ Bh, const ushort* __restrict__ Bl,
                                                   const float* __restrict__ asrc, const float* __restrict__ adst,
                                                   _Float16* __restrict__ H, float* __restrict__ a_s,
                                                   float* __restrict__ a_d, int M, int OC) {
  constexpr int BM = RT * 16;
  constexpr int NC = K / 32;
  __shared__ float sh_s[4][BM], sh_d[4][BM];
  int w = threadIdx.x >> 6, l = threadIdx.x & 63;
  int n0 = blockIdx.x * BM;
  int cw = blockIdx.y * (4 * NCT * 16) + w * (NCT * 16);
  int lr = l & 15;
  int g8 = (l >> 4) * 8;
  f32x4 acc[RT][NCT];
#pragma unroll
  for (int r = 0; r < RT; r++)
#pragma unroll
    for (int t = 0; t < NCT; t++) acc[r][t] = (f32x4){0.f, 0.f, 0.f, 0.f};
  int rows[RT];
#pragma unroll
  for (int r = 0; r < RT; r++) rows[r] = min(n0 + 16 * r + lr, M - 1);

  bf16x8 bh0[NCT], bl0[NCT], ah0[RT], al0[RT];
  bf16x8 bh1[NCT], bl1[NCT], ah1[RT], al1[RT];
  LOADC(0, bh0, bl0, ah0, al0);
#pragma unroll
  for (int c = 0; c < NC; c += 2) {   // NC is 4 or 8 (even)
    LOADC(c + 1, bh1, bl1, ah1, al1);
    MFMAC(bh0, bl0, ah0, al0);
    if (c + 2 < NC) LOADC(c + 2, bh0, bl0, ah0, al0);
    MFMAC(bh1, bl1, ah1, al1);
  }

  // H write (D layout: col = l&15, row = 4*(l>>4)+reg)
#pragma unroll
  for (int r = 0; r < RT; r++)
#pragma unroll
    for (int t = 0; t < NCT; t++)
#pragma unroll
      for (int reg = 0; reg < 4; reg++) {
        int row = n0 + 16 * r + (l >> 4) * 4 + reg;
        if (row < M) H[(size_t)row * OC + cw + 16 * t + lr] = (_Float16)acc[r][t][reg];
      }

  // fused attention scalars: per-wave partial over its NCT*16 cols, 16-lane reduce,
  // then cross-wave combine in LDS.
  float asv[NCT], adv[NCT];
#pragma unroll
  for (int t = 0; t < NCT; t++) {
    asv[t] = asrc[cw + 16 * t + lr];
    adv[t] = adst[cw + 16 * t + lr];
  }
#pragma unroll
  for (int r = 0; r < RT; r++) {
#pragma unroll
    for (int reg = 0; reg < 4; reg++) {
      float ps = 0.f, pd = 0.f;
#pragma unroll
      for (int t = 0; t < NCT; t++) {
        ps += acc[r][t][reg] * asv[t];
        pd += acc[r][t][reg] * adv[t];
      }
#pragma unroll
      for (int mask = 1; mask < 16; mask <<= 1) {
        ps += __shfl_xor(ps, mask, 64);
        pd += __shfl_xor(pd, mask, 64);
      }
      int rl = 16 * r + (l >> 4) * 4 + reg;
      if (lr == 0) { sh_s[w][rl] = ps; sh_d[w][rl] = pd; }
    }
  }
  __syncthreads();
  int tid = threadIdx.x;
  if (HEADS == 4) {
    // NCT==2: waves {0,1} -> head_local 0, {2,3} -> head_local 1 (2 heads/block)
    if (tid < 2 * BM) {
      int rr = tid & (BM - 1), hl = tid / BM;
      int row = n0 + rr;
      if (row < M) {
        int hidx = row * 4 + blockIdx.y * 2 + hl;
        a_s[hidx] = sh_s[2 * hl][rr] + sh_s[2 * hl + 1][rr];
        a_d[hidx] = sh_d[2 * hl][rr] + sh_d[2 * hl + 1][rr];
      }
    }
  } else {
    if (tid < BM) {
      int row = n0 + tid;
      if (row < M) {
        a_s[row] = sh_s[0][tid] + sh_s[1][tid] + sh_s[2][tid] + sh_s[3][tid];
        a_d[row] = sh_d[0][tid] + sh_d[1][tid] + sh_d[2][tid] + sh_d[3][tid];
      }
    }
  }
}
#undef LOADC
#undef MFMAC

// ---------------- fused edge-logit + segment softmax -> alpha (SoA by head) ----------------
__global__ __launch_bounds__(256) void k_alpha4(const float* __restrict__ a_s, const float* __restrict__ a_d,
                                                const int* __restrict__ row_start, const int* __restrict__ csr,
                                                float* __restrict__ el, float* __restrict__ sal) {
  int wid = threadIdx.x >> 6, l = threadIdx.x & 63;
  int n = blockIdx.x * 4 + wid;
  if (n >= NNODES) return;
  int head = l >> 4, sub = l & 15;
  int jb = row_start[n], je = row_start[n + 1];
  float ad = a_d[n * 4 + head];
  float es = leaky(a_s[n * 4 + head] + ad);
  float m = -1e30f, s = 0.f;
  if (sub == 0) { m = es; s = 1.f; }
  for (int j = jb + sub; j < je; j += 16) {
    float e = leaky(a_s[csr[j] * 4 + head] + ad);
    float nm = fmaxf(m, e);
    s = s * __expf(m - nm) + __expf(e - nm);
    m = nm;
  }
#pragma unroll
  for (int mask = 1; mask < 16; mask <<= 1) {
    float m2 = __shfl_xor(m, mask, 64);
    float s2 = __shfl_xor(s, mask, 64);
    float nm = fmaxf(m, m2);
    s = s * __expf(m - nm) + s2 * __expf(m2 - nm);
    m = nm;
  }
  float inv = 1.f / s;
  float* eh = el + (size_t)head * NEDGES;
  for (int j = jb + sub; j < je; j += 16) {
    float e = leaky(a_s[csr[j] * 4 + head] + ad);
    eh[j] = __expf(e - m) * inv;
  }
  if (sub == 0) sal[n * 4 + head] = __expf(es - m) * inv;
}

__global__ __launch_bounds__(256) void k_alpha1(const float* __restrict__ a_s, const float* __restrict__ a_d,
                                                const int* __restrict__ row_start, const int* __restrict__ csr,
                                                float* __restrict__ el, float* __restrict__ sal) {
  int wid = threadIdx.x >> 6, l = threadIdx.x & 63;
  int n = blockIdx.x * 4 + wid;
  if (n >= NNODES) return;
  int jb = row_start[n], je = row_start[n + 1];
  float ad = a_d[n];
  float es = leaky(a_s[n] + ad);
  float m = -1e30f, s = 0.f;
  if (l == 0) { m = es; s = 1.f; }
  for (int j = jb + l; j < je; j += 64) {
    float e = leaky(a_s[csr[j]] + ad);
    float nm = fmaxf(m, e);
    s = s * __expf(m - nm) + __expf(e - nm);
    m = nm;
  }
#pragma unroll
  for (int mask = 1; mask < 64; mask <<= 1) {
    float m2 = __shfl_xor(m, mask, 64);
    float s2 = __shfl_xor(s, mask, 64);
    float nm = fmaxf(m, m2);
    s = s * __expf(m - nm) + s2 * __expf(m2 - nm);
    m = nm;
  }
  float inv = 1.f / s;
  for (int j = jb + l; j < je; j += 64) el[j] = __expf(leaky(a_s[csr[j]] + ad) - m) * inv;
  if (l == 0) sal[n] = __expf(es - m) * inv;
}

// ---------------- gather-accumulate (alpha precomputed) ----------------
__global__ __launch_bounds__(256) void k_gath4(const _Float16* __restrict__ h, const int* __restrict__ row_start,
                                               const int* __restrict__ csr, const float* __restrict__ el,
                                               const float* __restrict__ sal, const float* __restrict__ bias,
                                               ushort* __restrict__ Ah, ushort* __restrict__ Al) {
  int wid = threadIdx.x >> 6, l = threadIdx.x & 63;
  int n = blockIdx.x * 4 + wid;
  if (n >= NNODES) return;
  int head = l >> 4;
  const float* eh = el + (size_t)head * NEDGES;
  int jb = row_start[n], je = row_start[n + 1];
  float sa = sal[n * 4 + head];
  f16x4 hv = *(const f16x4*)&h[(size_t)n * 256 + l * 4];
  float4 acc = {sa * (float)hv[0], sa * (float)hv[1], sa * (float)hv[2], sa * (float)hv[3]};
  int j = jb;
  for (; j + 3 < je; j += 4) {
    int s0 = csr[j], s1 = csr[j + 1], s2 = csr[j + 2], s3 = csr[j + 3];
    float a0 = eh[j], a1 = eh[j + 1], a2 = eh[j + 2], a3 = eh[j + 3];
    f16x4 v0 = *(const f16x4*)&h[(size_t)s0 * 256 + l * 4];
    f16x4 v1 = *(const f16x4*)&h[(size_t)s1 * 256 + l * 4];
    f16x4 v2 = *(const f16x4*)&h[(size_t)s2 * 256 + l * 4];
    f16x4 v3 = *(const f16x4*)&h[(size_t)s3 * 256 + l * 4];
    acc.x += a0 * (float)v0[0] + a1 * (float)v1[0] + a2 * (float)v2[0] + a3 * (float)v3[0];
    acc.y += a0 * (float)v0[1] + a1 * (float)v1[1] + a2 * (float)v2[1] + a3 * (float)v3[1];
    acc.z += a0 * (float)v0[2] + a1 * (float)v1[2] + a2 * (float)v2[2] + a3 * (float)v3[2];
    acc.w += a0 * (float)v0[3] + a1 * (float)v1[3] + a2 * (float)v2[3] + a3 * (float)v3[3];
  }
  for (; j < je; j++) {
    int s0 = csr[j];
    float a0 = eh[j];
    f16x4 v0 = *(const f16x4*)&h[(size_t)s0 * 256 + l * 4];
    acc.x += a0 * (float)v0[0]; acc.y += a0 * (float)v0[1];
    acc.z += a0 * (float)v0[2]; acc.w += a0 * (float)v0[3];
  }
  float4 b = *(const float4*)&bias[l * 4];
  float4 o;
  o.x = elu(acc.x + b.x); o.y = elu(acc.y + b.y);
  o.z = elu(acc.z + b.z); o.w = elu(acc.w + b.w);
  size_t base = (size_t)n * 256 + (l >> 3) * 32 + (l & 3) * 8 + (((l & 7) >= 4) ? 4 : 0);
  ushort4 hh, ll;
  hh.x = f2bf(o.x); ll.x = f2bf(o.x - bf2f(hh.x));
  hh.y = f2bf(o.y); ll.y = f2bf(o.y - bf2f(hh.y));
  hh.z = f2bf(o.z); ll.z = f2bf(o.z - bf2f(hh.z));
  hh.w = f2bf(o.w); ll.w = f2bf(o.w - bf2f(hh.w));
  *(ushort4*)&Ah[base] = hh;
  *(ushort4*)&Al[base] = ll;
}

// 1 head + fused MLP (64->32->1)
__global__ __launch_bounds__(256) void k_gath1(const _Float16* __restrict__ h, const int* __restrict__ row_start,
                                               const int* __restrict__ csr, const float* __restrict__ el,
                                               const float* __restrict__ sal, const float* __restrict__ bias,
                                               const float* __restrict__ w1, const float* __restrict__ b1,
                                               const float* __restrict__ w2, const float* __restrict__ b2,
                                               float* __restrict__ out) {
  __shared__ float sh[4][64];
  int wid = threadIdx.x >> 6, l = threadIdx.x & 63;
  int n = blockIdx.x * 4 + wid;
  float val = 0.f;
  if (n < NNODES) {
    int jb = row_start[n], je = row_start[n + 1];
    float acc = sal[n] * (float)h[(size_t)n * 64 + l];
    int j = jb;
    for (; j + 3 < je; j += 4) {
      int s0 = csr[j], s1 = csr[j + 1], s2 = csr[j + 2], s3 = csr[j + 3];
      float a0 = el[j], a1 = el[j + 1], a2 = el[j + 2], a3 = el[j + 3];
      float v0 = (float)h[(size_t)s0 * 64 + l];
      float v1 = (float)h[(size_t)s1 * 64 + l];
      float v2 = (float)h[(size_t)s2 * 64 + l];
      float v3 = (float)h[(size_t)s3 * 64 + l];
      acc += a0 * v0 + a1 * v1 + a2 * v2 + a3 * v3;
    }
    for (; j < je; j++) acc += el[j] * (float)h[(size_t)csr[j] * 64 + l];
    val = elu(acc + bias[l]);
  }
  sh[wid][l] = val;
  __syncthreads();
  float r = 0.f;
  if (l < 32 && n < NNODES) {
    r = b1[l];
#pragma unroll 8
    for (int k = 0; k < 64; k++) r += sh[wid][k] * w1[k * 32 + l];
    r = fmaxf(r, 0.f);
    r *= w2[l];
  }
  for (int mask = 16; mask >= 1; mask >>= 1) r += __shfl_xor(r, mask, 64);
  if (l == 0 && n < NNODES) out[n] = r + b2[0];
}

extern "C" void kernel_launch(void* const* d_in, const int* in_sizes, int n_in,
                              void* d_out, int out_size, void* d_ws, size_t ws_size,
                              hipStream_t stream) {
  const float* x    = (const float*)d_in[0];
  const int*   eidx = (const int*)d_in[1];
  const float* lin0 = (const float*)d_in[2];
  const float* as0  = (const float*)d_in[3];
  const float* ad0  = (const float*)d_in[4];
  const float* b0   = (const float*)d_in[5];
  const float* lin1 = (const float*)d_in[6];
  const float* as1  = (const float*)d_in[7];
  const float* ad1  = (const float*)d_in[8];
  const float* b1l  = (const float*)d_in[9];
  const float* lin2 = (const float*)d_in[10];
  const float* as2  = (const float*)d_in[11];
  const float* ad2  = (const float*)d_in[12];
  const float* b2l  = (const float*)d_in[13];
  const float* w1   = (const float*)d_in[14];
  const float* mb1  = (const float*)d_in[15];
  const float* w2   = (const float*)d_in[16];
  const float* mb2  = (const float*)d_in[17];
  float* outp = (float*)d_out;

  const int* srcA = eidx;
  const int* dstA = eidx + NEDGES;

  char* ws = (char*)d_ws;
  size_t o = 0;
  auto alloc = [&](size_t bytes) { size_t r = o; o += (bytes + 255) & ~255UL; return r; };
  _Float16* h16 = (_Float16*)(ws + alloc((size_t)NNODES * 256 * 2));
  ushort* Ahp = (ushort*)(ws + alloc((size_t)NNODES * 256 * 2));
  ushort* Alp = (ushort*)(ws + alloc((size_t)NNODES * 256 * 2));
  ushort* wh  = (ushort*)(ws + alloc(256 * 256 * 2));
  ushort* wl  = (ushort*)(ws + alloc(256 * 256 * 2));
  float*  el  = (float*)(ws + alloc((size_t)NEDGES * 4 * 4));
  float*  vas = (float*)(ws + alloc((size_t)NNODES * 4 * 4));
  float*  vad = (float*)(ws + alloc((size_t)NNODES * 4 * 4));
  float*  sal = (float*)(ws + alloc((size_t)NNODES * 4 * 4));
  int* row_start = (int*)(ws + alloc((NNODES + 1) * 4));
  int* fill      = (int*)(ws + alloc(NNODES * 4));
  int* csr       = (int*)(ws + alloc(NEDGES * 4));
  int* blocksum  = (int*)(ws + alloc(SCAN_NB * 4));
  int* blockoff  = (int*)(ws + alloc(SCAN_NB * 4));

  // Build dst-sorted CSR (self-loops handled implicitly via sal)
  k_zero<<<(NNODES + 255) / 256, 256, 0, stream>>>(fill, NNODES);
  k_hist<<<(NEDGES + 255) / 256, 256, 0, stream>>>(dstA, fill, NEDGES);
  k_scan1<<<SCAN_NB, 256, 0, stream>>>(fill, row_start, blocksum, NNODES);
  k_scan2<<<1, 128, 0, stream>>>(blocksum, blockoff, row_start, SCAN_NB, NNODES);
  k_scan3<<<SCAN_NB, 256, 0, stream>>>(row_start, blockoff, fill, NNODES);
  k_scatter<<<(NEDGES + 255) / 256, 256, 0, stream>>>(srcA, dstA, row_start, fill, csr, NEDGES);

  dim3 g44((NNODES + 31) / 32, 2);   // 4-head GEMMs: BM=32, 128 cols/block
  dim3 g21((NNODES + 15) / 16, 1);   // 1-head GEMM:  BM=16, 64 cols/block

  // ---- layer 0 (IN=128 -> 4x64, concat) ----
  k_cvt_pack<<<(NNODES * 4 + 255) / 256, 256, 0, stream>>>(x, Ahp, Alp, NNODES * 4);
  k_prep_w<<<(256 * 4 + 255) / 256, 256, 0, stream>>>(lin0, wh, wl, 128, 256);
  k_gemm_mfma<128, 2, 4, 2><<<g44, 256, 0, stream>>>(Ahp, Alp, wh, wl, as0, ad0, h16, vas, vad, NNODES, 256);
  k_alpha4<<<5000, 256, 0, stream>>>(vas, vad, row_start, csr, el, sal);
  k_gath4<<<5000, 256, 0, stream>>>(h16, row_start, csr, el, sal, b0, Ahp, Alp);

  // ---- layer 1 (256 -> 4x64, concat) ----
  k_prep_w<<<(256 * 8 + 255) / 256, 256, 0, stream>>>(lin1, wh, wl, 256, 256);
  k_gemm_mfma<256, 2, 4, 2><<<g44, 256, 0, stream>>>(Ahp, Alp, wh, wl, as1, ad1, h16, vas, vad, NNODES, 256);
  k_alpha4<<<5000, 256, 0, stream>>>(vas, vad, row_start, csr, el, sal);
  k_gath4<<<5000, 256, 0, stream>>>(h16, row_start, csr, el, sal, b1l, Ahp, Alp);

  // ---- layer 2 (256 -> 64, 1 head, mean) + MLP ----
  k_prep_w<<<(64 * 8 + 255) / 256, 256, 0, stream>>>(lin2, wh, wl, 256, 64);
  k_gemm_mfma<256, 1, 1, 1><<<g21, 256, 0, stream>>>(Ahp, Alp, wh, wl, as2, ad2, h16, vas, vad, NNODES, 64);
  k_alpha1<<<5000, 256, 0, stream>>>(vas, vad, row_start, csr, el, sal);
  k_gath1<<<5000, 256, 0, stream>>>(h16, row_start, csr, el, sal, b2l, w1, mb1, w2, mb2, outp);
}

// Round 8
// 224.862 us; speedup vs baseline: 1.1664x; 1.1664x over previous
//
#include <hip/hip_runtime.h>

#define NNODES 20000
#define NEDGES 320000
#define SCAN_NB ((NNODES + 255) / 256)   // 79

typedef __attribute__((ext_vector_type(8))) short bf16x8;
typedef __attribute__((ext_vector_type(4))) float f32x4;
typedef _Float16 f16x4 __attribute__((ext_vector_type(4)));

__device__ __forceinline__ float leaky(float x) { return x > 0.f ? x : 0.2f * x; }
__device__ __forceinline__ float elu(float x) { return x > 0.f ? x : expm1f(x); }

__device__ __forceinline__ ushort f2bf(float f) {
  uint u = __float_as_uint(f);
  uint r = (u + 0x7fffu + ((u >> 16) & 1u)) >> 16;
  return (ushort)r;
}
__device__ __forceinline__ float bf2f(ushort h) {
  return __uint_as_float(((uint)h) << 16);
}

// async 16B global->LDS (DMA; zero VGPR cost; compiler cannot serialize it)
__device__ __forceinline__ void gll16(const ushort* g, ushort* l) {
  __builtin_amdgcn_global_load_lds((const __attribute__((address_space(1))) void*)g,
                                   (__attribute__((address_space(3))) void*)l, 16, 0, 0);
}

// ---------------- CSR build ----------------
__global__ void k_zero(int* __restrict__ p, int n) {
  int i = blockIdx.x * blockDim.x + threadIdx.x;
  if (i < n) p[i] = 0;
}

__global__ void k_hist(const int* __restrict__ dst, int* __restrict__ cnt, int e) {
  int i = blockIdx.x * blockDim.x + threadIdx.x;
  if (i < e) atomicAdd(&cnt[dst[i]], 1);
}

__global__ __launch_bounds__(256) void k_scan1(const int* __restrict__ cnt, int* __restrict__ row_start,
                                               int* __restrict__ blocksum, int n) {
  __shared__ int s[256];
  int t = threadIdx.x;
  int i = blockIdx.x * 256 + t;
  int v = (i < n) ? cnt[i] : 0;
  s[t] = v;
  __syncthreads();
  for (int off = 1; off < 256; off <<= 1) {
    int x = (t >= off) ? s[t - off] : 0;
    __syncthreads();
    s[t] += x;
    __syncthreads();
  }
  if (i < n) row_start[i] = s[t] - v;
  if (t == 255) blocksum[blockIdx.x] = s[255];
}

__global__ __launch_bounds__(128) void k_scan2(int* __restrict__ blocksum, int* __restrict__ blockoff,
                                               int* __restrict__ row_start, int nb, int n) {
  __shared__ int s[128];
  int t = threadIdx.x;
  int v = (t < nb) ? blocksum[t] : 0;
  s[t] = v;
  __syncthreads();
  for (int off = 1; off < 128; off <<= 1) {
    int x = (t >= off) ? s[t - off] : 0;
    __syncthreads();
    s[t] += x;
    __syncthreads();
  }
  if (t < nb) blockoff[t] = s[t] - v;
  if (t == nb - 1) row_start[n] = s[t];
}

__global__ __launch_bounds__(256) void k_scan3(int* __restrict__ row_start, const int* __restrict__ blockoff,
                                               int* __restrict__ fill, int n) {
  int i = blockIdx.x * 256 + threadIdx.x;
  if (i < n) {
    row_start[i] += blockoff[blockIdx.x];
    fill[i] = 0;
  }
}

__global__ void k_scatter(const int* __restrict__ src, const int* __restrict__ dst,
                          const int* __restrict__ row_start, int* __restrict__ fill,
                          int* __restrict__ csr, int e) {
  int i = blockIdx.x * blockDim.x + threadIdx.x;
  if (i < e) {
    int d = dst[i];
    int p = row_start[d] + atomicAdd(&fill[d], 1);
    csr[p] = src[i];
  }
}

// ---------------- fp32 -> packed hi/lo bf16 (MFMA fragment order) ----------------
// Within each 32-k chunk (64B), granule g (8 ushorts) holds the fragment for lane-group g.
__global__ void k_cvt_pack(const float* __restrict__ a, ushort* __restrict__ hi,
                           ushort* __restrict__ lo, int total) {
  int i = blockIdx.x * blockDim.x + threadIdx.x;
  if (i >= total) return;
  const float* src = a + (size_t)i * 32;
  ushort h[32], lw[32];
#pragma unroll
  for (int r = 0; r < 32; r++) {
    int p = (r < 16) ? ((r >> 2) * 8 + (r & 3)) : (((r - 16) >> 2) * 8 + 4 + (r & 3));
    float v = src[r];
    ushort hh = f2bf(v);
    h[p] = hh;
    lw[p] = f2bf(v - bf2f(hh));
  }
  ushort* ho = hi + (size_t)i * 32;
  ushort* llo = lo + (size_t)i * 32;
#pragma unroll
  for (int q = 0; q < 4; q++) {
    *(bf16x8*)&ho[q * 8] = *(bf16x8*)&h[q * 8];
    *(bf16x8*)&llo[q * 8] = *(bf16x8*)&lw[q * 8];
  }
}

__global__ void k_prep_w(const float* __restrict__ w, ushort* __restrict__ th,
                         ushort* __restrict__ tl, int K, int OC) {
  int i = blockIdx.x * blockDim.x + threadIdx.x;
  int KC = K / 32;
  if (i >= OC * KC) return;
  int oc = i / KC, c = i % KC;
  ushort h[32], lw[32];
#pragma unroll
  for (int r = 0; r < 32; r++) {
    int p = (r < 16) ? ((r >> 2) * 8 + (r & 3)) : (((r - 16) >> 2) * 8 + 4 + (r & 3));
    float v = w[(size_t)(c * 32 + r) * OC + oc];
    ushort hh = f2bf(v);
    h[p] = hh;
    lw[p] = f2bf(v - bf2f(hh));
  }
  ushort* ho = th + (size_t)oc * K + c * 32;
  ushort* llo = tl + (size_t)oc * K + c * 32;
#pragma unroll
  for (int q = 0; q < 4; q++) {
    *(bf16x8*)&ho[q * 8] = *(bf16x8*)&h[q * 8];
    *(bf16x8*)&llo[q * 8] = *(bf16x8*)&lw[q * 8];
  }
}

// ---------------- MFMA GEMM: async LDS double-buffer (canonical §5), fused asd epilogue ----
// Block: 4 waves; tile BM=64 rows x BN=NCT*64 cols; BK=32 chunks.
// Staging: global_load_lds width 16, LDS linear; source pre-swizzled so LDS slot
// (row, q) holds fragment granule g = q ^ ((row>>1)&3)  -> ds_read_b128 is 2-way (free).
template <int K, int NCT, int HEADS>
__global__ __launch_bounds__(256) void k_gemm_mfma(const ushort* __restrict__ Ah, const ushort* __restrict__ Al,
                                                   const ushort* __restrict__ Bh, const ushort* __restrict__ Bl,
                                                   const float* __restrict__ asrc, const float* __restrict__ adst,
                                                   _Float16* __restrict__ H, float* __restrict__ a_s,
                                                   float* __restrict__ a_d, int M, int OC) {
  constexpr int BM = 64, BN = NCT * 64, NC = K / 32;
  constexpr int ALO = 2048;              // ushort offsets within a buffer
  constexpr int BOFF = 4096;
  constexpr int BLO = BOFF + BN * 32;
  constexpr int BUFE = BOFF + BN * 64;   // total ushorts per buffer
  __shared__ ushort sb0[BUFE], sb1[BUFE];
  __shared__ float sh_s[4][64], sh_d[4][64];
  int w = threadIdx.x >> 6, l = threadIdx.x & 63;
  int n0 = blockIdx.x * BM;
  int cw = blockIdx.y * BN + w * (NCT * 16);  // wave's global col base
  int lr = l & 15;

  // ---- per-lane staging sources (fragment-granule pre-swizzled) ----
  int q = l & 3;
  int srow = 16 * w + (l >> 2);
  int sgrow = min(n0 + srow, M - 1);
  int gA = q ^ ((srow >> 1) & 3);
  const ushort* aH = Ah + (size_t)sgrow * K + gA * 8;
  const ushort* aL = Al + (size_t)sgrow * K + gA * 8;
  const ushort* bH[NCT];
  const ushort* bL[NCT];
  int colb[NCT];
#pragma unroll
  for (int i = 0; i < NCT; i++) {
    colb[i] = 16 * NCT * w + 16 * i;
    int sc = colb[i] + (l >> 2);
    int gB = q ^ ((sc >> 1) & 3);
    bH[i] = Bh + (size_t)(blockIdx.y * BN + sc) * K + gB * 8;
    bL[i] = Bl + (size_t)(blockIdx.y * BN + sc) * K + gB * 8;
  }

#define STAGE(buf, c)                                              \
  {                                                                \
    gll16(aH + (c) * 32, &buf[0 + w * 512]);                       \
    gll16(aL + (c) * 32, &buf[ALO + w * 512]);                     \
    _Pragma("unroll") for (int i = 0; i < NCT; i++) {              \
      gll16(bH[i] + (c) * 32, &buf[BOFF + colb[i] * 32]);          \
      gll16(bL[i] + (c) * 32, &buf[BLO + colb[i] * 32]);           \
    }                                                              \
  }

  f32x4 acc[4][NCT];
#pragma unroll
  for (int r = 0; r < 4; r++)
#pragma unroll
    for (int t = 0; t < NCT; t++) acc[r][t] = (f32x4){0.f, 0.f, 0.f, 0.f};

#define COMP(buf)                                                                   \
  {                                                                                 \
    bf16x8 bhf[NCT], blf[NCT];                                                      \
    _Pragma("unroll") for (int t = 0; t < NCT; t++) {                               \
      int bcol = 16 * NCT * w + 16 * t + lr;                                        \
      int gb = (l >> 4) ^ ((bcol >> 1) & 3);                                        \
      bhf[t] = *(const bf16x8*)&buf[BOFF + bcol * 32 + gb * 8];                     \
      blf[t] = *(const bf16x8*)&buf[BLO + bcol * 32 + gb * 8];                      \
    }                                                                               \
    _Pragma("unroll") for (int r = 0; r < 4; r++) {                                 \
      int arow = 16 * r + lr;                                                       \
      int ga = (l >> 4) ^ ((arow >> 1) & 3);                                        \
      bf16x8 ahf = *(const bf16x8*)&buf[arow * 32 + ga * 8];                        \
      bf16x8 alf = *(const bf16x8*)&buf[ALO + arow * 32 + ga * 8];                  \
      _Pragma("unroll") for (int t = 0; t < NCT; t++) {                             \
        acc[r][t] = __builtin_amdgcn_mfma_f32_16x16x32_bf16(ahf, bhf[t], acc[r][t], 0, 0, 0); \
        acc[r][t] = __builtin_amdgcn_mfma_f32_16x16x32_bf16(alf, bhf[t], acc[r][t], 0, 0, 0); \
        acc[r][t] = __builtin_amdgcn_mfma_f32_16x16x32_bf16(ahf, blf[t], acc[r][t], 0, 0, 0); \
      }                                                                             \
    }                                                                               \
  }

  ushort* cur = sb0;
  ushort* nxt = sb1;
  STAGE(cur, 0);
  __syncthreads();   // drains vmcnt (compiler emits vmcnt(0) before s_barrier)
  for (int c = 0; c < NC; ++c) {
    if (c + 1 < NC) STAGE(nxt, c + 1);
    COMP(cur);
    __syncthreads();
    ushort* tmp = cur; cur = nxt; nxt = tmp;
  }
#undef STAGE
#undef COMP

  // H write (D layout: col = l&15, row = 4*(l>>4)+reg)
#pragma unroll
  for (int r = 0; r < 4; r++)
#pragma unroll
    for (int t = 0; t < NCT; t++)
#pragma unroll
      for (int reg = 0; reg < 4; reg++) {
        int row = n0 + 16 * r + (l >> 4) * 4 + reg;
        if (row < M) H[(size_t)row * OC + cw + 16 * t + lr] = (_Float16)acc[r][t][reg];
      }

  // fused attention scalars
  float asv[NCT], adv[NCT];
#pragma unroll
  for (int t = 0; t < NCT; t++) {
    asv[t] = asrc[cw + 16 * t + lr];
    adv[t] = adst[cw + 16 * t + lr];
  }
#pragma unroll
  for (int r = 0; r < 4; r++) {
#pragma unroll
    for (int reg = 0; reg < 4; reg++) {
      float ps = 0.f, pd = 0.f;
#pragma unroll
      for (int t = 0; t < NCT; t++) {
        ps += acc[r][t][reg] * asv[t];
        pd += acc[r][t][reg] * adv[t];
      }
#pragma unroll
      for (int mask = 1; mask < 16; mask <<= 1) {
        ps += __shfl_xor(ps, mask, 64);
        pd += __shfl_xor(pd, mask, 64);
      }
      int rl = 16 * r + (l >> 4) * 4 + reg;
      if (lr == 0) { sh_s[w][rl] = ps; sh_d[w][rl] = pd; }
    }
  }
  __syncthreads();
  int tid = threadIdx.x;
  if (HEADS == 4) {
    // BN=128: cols [0,64) = head blockIdx.y*2, cols [64,128) = +1; waves {0,1},{2,3}
    if (tid < 128) {
      int rr = tid & 63, hl = tid >> 6;
      int row = n0 + rr;
      if (row < M) {
        int hidx = row * 4 + blockIdx.y * 2 + hl;
        a_s[hidx] = sh_s[2 * hl][rr] + sh_s[2 * hl + 1][rr];
        a_d[hidx] = sh_d[2 * hl][rr] + sh_d[2 * hl + 1][rr];
      }
    }
  } else {
    if (tid < 64) {
      int row = n0 + tid;
      if (row < M) {
        a_s[row] = sh_s[0][tid] + sh_s[1][tid] + sh_s[2][tid] + sh_s[3][tid];
        a_d[row] = sh_d[0][tid] + sh_d[1][tid] + sh_d[2][tid] + sh_d[3][tid];
      }
    }
  }
}

// ---------------- fused edge-logit + segment softmax -> alpha (SoA by head) ----------------
__global__ __launch_bounds__(256) void k_alpha4(const float* __restrict__ a_s, const float* __restrict__ a_d,
                                                const int* __restrict__ row_start, const int* __restrict__ csr,
                                                float* __restrict__ el, float* __restrict__ sal) {
  int wid = threadIdx.x >> 6, l = threadIdx.x & 63;
  int n = blockIdx.x * 4 + wid;
  if (n >= NNODES) return;
  int head = l >> 4, sub = l & 15;
  int jb = row_start[n], je = row_start[n + 1];
  float ad = a_d[n * 4 + head];
  float es = leaky(a_s[n * 4 + head] + ad);
  float m = -1e30f, s = 0.f;
  if (sub == 0) { m = es; s = 1.f; }
  for (int j = jb + sub; j < je; j += 16) {
    float e = leaky(a_s[csr[j] * 4 + head] + ad);
    float nm = fmaxf(m, e);
    s = s * __expf(m - nm) + __expf(e - nm);
    m = nm;
  }
#pragma unroll
  for (int mask = 1; mask < 16; mask <<= 1) {
    float m2 = __shfl_xor(m, mask, 64);
    float s2 = __shfl_xor(s, mask, 64);
    float nm = fmaxf(m, m2);
    s = s * __expf(m - nm) + s2 * __expf(m2 - nm);
    m = nm;
  }
  float inv = 1.f / s;
  float* eh = el + (size_t)head * NEDGES;
  for (int j = jb + sub; j < je; j += 16) {
    float e = leaky(a_s[csr[j] * 4 + head] + ad);
    eh[j] = __expf(e - m) * inv;
  }
  if (sub == 0) sal[n * 4 + head] = __expf(es - m) * inv;
}

__global__ __launch_bounds__(256) void k_alpha1(const float* __restrict__ a_s, const float* __restrict__ a_d,
                                                const int* __restrict__ row_start, const int* __restrict__ csr,
                                                float* __restrict__ el, float* __restrict__ sal) {
  int wid = threadIdx.x >> 6, l = threadIdx.x & 63;
  int n = blockIdx.x * 4 + wid;
  if (n >= NNODES) return;
  int jb = row_start[n], je = row_start[n + 1];
  float ad = a_d[n];
  float es = leaky(a_s[n] + ad);
  float m = -1e30f, s = 0.f;
  if (l == 0) { m = es; s = 1.f; }
  for (int j = jb + l; j < je; j += 64) {
    float e = leaky(a_s[csr[j]] + ad);
    float nm = fmaxf(m, e);
    s = s * __expf(m - nm) + __expf(e - nm);
    m = nm;
  }
#pragma unroll
  for (int mask = 1; mask < 64; mask <<= 1) {
    float m2 = __shfl_xor(m, mask, 64);
    float s2 = __shfl_xor(s, mask, 64);
    float nm = fmaxf(m, m2);
    s = s * __expf(m - nm) + s2 * __expf(m2 - nm);
    m = nm;
  }
  float inv = 1.f / s;
  for (int j = jb + l; j < je; j += 64) el[j] = __expf(leaky(a_s[csr[j]] + ad) - m) * inv;
  if (l == 0) sal[n] = __expf(es - m) * inv;
}

// ---------------- gather-accumulate (alpha precomputed) ----------------
__global__ __launch_bounds__(256) void k_gath4(const _Float16* __restrict__ h, const int* __restrict__ row_start,
                                               const int* __restrict__ csr, const float* __restrict__ el,
                                               const float* __restrict__ sal, const float* __restrict__ bias,
                                               ushort* __restrict__ Ah, ushort* __restrict__ Al) {
  int wid = threadIdx.x >> 6, l = threadIdx.x & 63;
  int n = blockIdx.x * 4 + wid;
  if (n >= NNODES) return;
  int head = l >> 4;
  const float* eh = el + (size_t)head * NEDGES;
  int jb = row_start[n], je = row_start[n + 1];
  float sa = sal[n * 4 + head];
  f16x4 hv = *(const f16x4*)&h[(size_t)n * 256 + l * 4];
  float4 acc = {sa * (float)hv[0], sa * (float)hv[1], sa * (float)hv[2], sa * (float)hv[3]};
  int j = jb;
  for (; j + 3 < je; j += 4) {
    int s0 = csr[j], s1 = csr[j + 1], s2 = csr[j + 2], s3 = csr[j + 3];
    float a0 = eh[j], a1 = eh[j + 1], a2 = eh[j + 2], a3 = eh[j + 3];
    f16x4 v0 = *(const f16x4*)&h[(size_t)s0 * 256 + l * 4];
    f16x4 v1 = *(const f16x4*)&h[(size_t)s1 * 256 + l * 4];
    f16x4 v2 = *(const f16x4*)&h[(size_t)s2 * 256 + l * 4];
    f16x4 v3 = *(const f16x4*)&h[(size_t)s3 * 256 + l * 4];
    acc.x += a0 * (float)v0[0] + a1 * (float)v1[0] + a2 * (float)v2[0] + a3 * (float)v3[0];
    acc.y += a0 * (float)v0[1] + a1 * (float)v1[1] + a2 * (float)v2[1] + a3 * (float)v3[1];
    acc.z += a0 * (float)v0[2] + a1 * (float)v1[2] + a2 * (float)v2[2] + a3 * (float)v3[2];
    acc.w += a0 * (float)v0[3] + a1 * (float)v1[3] + a2 * (float)v2[3] + a3 * (float)v3[3];
  }
  for (; j < je; j++) {
    int s0 = csr[j];
    float a0 = eh[j];
    f16x4 v0 = *(const f16x4*)&h[(size_t)s0 * 256 + l * 4];
    acc.x += a0 * (float)v0[0]; acc.y += a0 * (float)v0[1];
    acc.z += a0 * (float)v0[2]; acc.w += a0 * (float)v0[3];
  }
  float4 b = *(const float4*)&bias[l * 4];
  float4 o;
  o.x = elu(acc.x + b.x); o.y = elu(acc.y + b.y);
  o.z = elu(acc.z + b.z); o.w = elu(acc.w + b.w);
  size_t base = (size_t)n * 256 + (l >> 3) * 32 + (l & 3) * 8 + (((l & 7) >= 4) ? 4 : 0);
  ushort4 hh, ll;
  hh.x = f2bf(o.x); ll.x = f2bf(o.x - bf2f(hh.x));
  hh.y = f2bf(o.y); ll.y = f2bf(o.y - bf2f(hh.y));
  hh.z = f2bf(o.z); ll.z = f2bf(o.z - bf2f(hh.z));
  hh.w = f2bf(o.w); ll.w = f2bf(o.w - bf2f(hh.w));
  *(ushort4*)&Ah[base] = hh;
  *(ushort4*)&Al[base] = ll;
}

// 1 head + fused MLP (64->32->1)
__global__ __launch_bounds__(256) void k_gath1(const _Float16* __restrict__ h, const int* __restrict__ row_start,
                                               const int* __restrict__ csr, const float* __restrict__ el,
                                               const float* __restrict__ sal, const float* __restrict__ bias,
                                               const float* __restrict__ w1, const float* __restrict__ b1,
                                               const float* __restrict__ w2, const float* __restrict__ b2,
                                               float* __restrict__ out) {
  __shared__ float sh[4][64];
  int wid = threadIdx.x >> 6, l = threadIdx.x & 63;
  int n = blockIdx.x * 4 + wid;
  float val = 0.f;
  if (n < NNODES) {
    int jb = row_start[n], je = row_start[n + 1];
    float acc = sal[n] * (float)h[(size_t)n * 64 + l];
    int j = jb;
    for (; j + 3 < je; j += 4) {
      int s0 = csr[j], s1 = csr[j + 1], s2 = csr[j + 2], s3 = csr[j + 3];
      float a0 = el[j], a1 = el[j + 1], a2 = el[j + 2], a3 = el[j + 3];
      float v0 = (float)h[(size_t)s0 * 64 + l];
      float v1 = (float)h[(size_t)s1 * 64 + l];
      float v2 = (float)h[(size_t)s2 * 64 + l];
      float v3 = (float)h[(size_t)s3 * 64 + l];
      acc += a0 * v0 + a1 * v1 + a2 * v2 + a3 * v3;
    }
    for (; j < je; j++) acc += el[j] * (float)h[(size_t)csr[j] * 64 + l];
    val = elu(acc + bias[l]);
  }
  sh[wid][l] = val;
  __syncthreads();
  float r = 0.f;
  if (l < 32 && n < NNODES) {
    r = b1[l];
#pragma unroll 8
    for (int k = 0; k < 64; k++) r += sh[wid][k] * w1[k * 32 + l];
    r = fmaxf(r, 0.f);
    r *= w2[l];
  }
  for (int mask = 16; mask >= 1; mask >>= 1) r += __shfl_xor(r, mask, 64);
  if (l == 0 && n < NNODES) out[n] = r + b2[0];
}

extern "C" void kernel_launch(void* const* d_in, const int* in_sizes, int n_in,
                              void* d_out, int out_size, void* d_ws, size_t ws_size,
                              hipStream_t stream) {
  const float* x    = (const float*)d_in[0];
  const int*   eidx = (const int*)d_in[1];
  const float* lin0 = (const float*)d_in[2];
  const float* as0  = (const float*)d_in[3];
  const float* ad0  = (const float*)d_in[4];
  const float* b0   = (const float*)d_in[5];
  const float* lin1 = (const float*)d_in[6];
  const float* as1  = (const float*)d_in[7];
  const float* ad1  = (const float*)d_in[8];
  const float* b1l  = (const float*)d_in[9];
  const float* lin2 = (const float*)d_in[10];
  const float* as2  = (const float*)d_in[11];
  const float* ad2  = (const float*)d_in[12];
  const float* b2l  = (const float*)d_in[13];
  const float* w1   = (const float*)d_in[14];
  const float* mb1  = (const float*)d_in[15];
  const float* w2   = (const float*)d_in[16];
  const float* mb2  = (const float*)d_in[17];
  float* outp = (float*)d_out;

  const int* srcA = eidx;
  const int* dstA = eidx + NEDGES;

  char* ws = (char*)d_ws;
  size_t o = 0;
  auto alloc = [&](size_t bytes) { size_t r = o; o += (bytes + 255) & ~255UL; return r; };
  _Float16* h16 = (_Float16*)(ws + alloc((size_t)NNODES * 256 * 2));
  ushort* Ahp = (ushort*)(ws + alloc((size_t)NNODES * 256 * 2));
  ushort* Alp = (ushort*)(ws + alloc((size_t)NNODES * 256 * 2));
  ushort* wh  = (ushort*)(ws + alloc(256 * 256 * 2));
  ushort* wl  = (ushort*)(ws + alloc(256 * 256 * 2));
  float*  el  = (float*)(ws + alloc((size_t)NEDGES * 4 * 4));
  float*  vas = (float*)(ws + alloc((size_t)NNODES * 4 * 4));
  float*  vad = (float*)(ws + alloc((size_t)NNODES * 4 * 4));
  float*  sal = (float*)(ws + alloc((size_t)NNODES * 4 * 4));
  int* row_start = (int*)(ws + alloc((NNODES + 1) * 4));
  int* fill      = (int*)(ws + alloc(NNODES * 4));
  int* csr       = (int*)(ws + alloc(NEDGES * 4));
  int* blocksum  = (int*)(ws + alloc(SCAN_NB * 4));
  int* blockoff  = (int*)(ws + alloc(SCAN_NB * 4));

  // Build dst-sorted CSR (self-loops handled implicitly via sal)
  k_zero<<<(NNODES + 255) / 256, 256, 0, stream>>>(fill, NNODES);
  k_hist<<<(NEDGES + 255) / 256, 256, 0, stream>>>(dstA, fill, NEDGES);
  k_scan1<<<SCAN_NB, 256, 0, stream>>>(fill, row_start, blocksum, NNODES);
  k_scan2<<<1, 128, 0, stream>>>(blocksum, blockoff, row_start, SCAN_NB, NNODES);
  k_scan3<<<SCAN_NB, 256, 0, stream>>>(row_start, blockoff, fill, NNODES);
  k_scatter<<<(NEDGES + 255) / 256, 256, 0, stream>>>(srcA, dstA, row_start, fill, csr, NEDGES);

  dim3 g44((NNODES + 63) / 64, 2);   // 4-head GEMMs: BM=64, BN=128
  dim3 g21((NNODES + 63) / 64, 1);   // 1-head GEMM:  BM=64, BN=64

  // ---- layer 0 (IN=128 -> 4x64, concat) ----
  k_cvt_pack<<<(NNODES * 4 + 255) / 256, 256, 0, stream>>>(x, Ahp, Alp, NNODES * 4);
  k_prep_w<<<(256 * 4 + 255) / 256, 256, 0, stream>>>(lin0, wh, wl, 128, 256);
  k_gemm_mfma<128, 2, 4><<<g44, 256, 0, stream>>>(Ahp, Alp, wh, wl, as0, ad0, h16, vas, vad, NNODES, 256);
  k_alpha4<<<5000, 256, 0, stream>>>(vas, vad, row_start, csr, el, sal);
  k_gath4<<<5000, 256, 0, stream>>>(h16, row_start, csr, el, sal, b0, Ahp, Alp);

  // ---- layer 1 (256 -> 4x64, concat) ----
  k_prep_w<<<(256 * 8 + 255) / 256, 256, 0, stream>>>(lin1, wh, wl, 256, 256);
  k_gemm_mfma<256, 2, 4><<<g44, 256, 0, stream>>>(Ahp, Alp, wh, wl, as1, ad1, h16, vas, vad, NNODES, 256);
  k_alpha4<<<5000, 256, 0, stream>>>(vas, vad, row_start, csr, el, sal);
  k_gath4<<<5000, 256, 0, stream>>>(h16, row_start, csr, el, sal, b1l, Ahp, Alp);

  // ---- layer 2 (256 -> 64, 1 head, mean) + MLP ----
  k_prep_w<<<(64 * 8 + 255) / 256, 256, 0, stream>>>(lin2, wh, wl, 256, 64);
  k_gemm_mfma<256, 1, 1><<<g21, 256, 0, stream>>>(Ahp, Alp, wh, wl, as2, ad2, h16, vas, vad, NNODES, 64);
  k_alpha1<<<5000, 256, 0, stream>>>(vas, vad, row_start, csr, el, sal);
  k_gath1<<<5000, 256, 0, stream>>>(h16, row_start, csr, el, sal, b2l, w1, mb1, w2, mb2, outp);
}

// Round 9
// 209.121 us; speedup vs baseline: 1.2542x; 1.0753x over previous
//
#include <hip/hip_runtime.h>

#define NNODES 20000
#define NEDGES 320000
#define SCAN_NB ((NNODES + 255) / 256)   // 79

typedef __attribute__((ext_vector_type(8))) short bf16x8;
typedef __attribute__((ext_vector_type(4))) float f32x4;
typedef _Float16 f16x4 __attribute__((ext_vector_type(4)));

__device__ __forceinline__ float leaky(float x) { return x > 0.f ? x : 0.2f * x; }
__device__ __forceinline__ float elu(float x) { return x > 0.f ? x : expm1f(x); }

__device__ __forceinline__ ushort f2bf(float f) {
  uint u = __float_as_uint(f);
  uint r = (u + 0x7fffu + ((u >> 16) & 1u)) >> 16;
  return (ushort)r;
}
__device__ __forceinline__ float bf2f(ushort h) {
  return __uint_as_float(((uint)h) << 16);
}

// async 16B global->LDS (DMA; zero VGPR cost; compiler cannot serialize it)
__device__ __forceinline__ void gll16(const ushort* g, ushort* l) {
  __builtin_amdgcn_global_load_lds((const __attribute__((address_space(1))) void*)g,
                                   (__attribute__((address_space(3))) void*)l, 16, 0, 0);
}

// ---------------- CSR build ----------------
__global__ void k_zero(int* __restrict__ p, int n) {
  int i = blockIdx.x * blockDim.x + threadIdx.x;
  if (i < n) p[i] = 0;
}

__global__ void k_hist(const int* __restrict__ dst, int* __restrict__ cnt, int e) {
  int i = blockIdx.x * blockDim.x + threadIdx.x;
  if (i < e) atomicAdd(&cnt[dst[i]], 1);
}

__global__ __launch_bounds__(256) void k_scan1(const int* __restrict__ cnt, int* __restrict__ row_start,
                                               int* __restrict__ blocksum, int n) {
  __shared__ int s[256];
  int t = threadIdx.x;
  int i = blockIdx.x * 256 + t;
  int v = (i < n) ? cnt[i] : 0;
  s[t] = v;
  __syncthreads();
  for (int off = 1; off < 256; off <<= 1) {
    int x = (t >= off) ? s[t - off] : 0;
    __syncthreads();
    s[t] += x;
    __syncthreads();
  }
  if (i < n) row_start[i] = s[t] - v;
  if (t == 255) blocksum[blockIdx.x] = s[255];
}

__global__ __launch_bounds__(128) void k_scan2(int* __restrict__ blocksum, int* __restrict__ blockoff,
                                               int* __restrict__ row_start, int nb, int n) {
  __shared__ int s[128];
  int t = threadIdx.x;
  int v = (t < nb) ? blocksum[t] : 0;
  s[t] = v;
  __syncthreads();
  for (int off = 1; off < 128; off <<= 1) {
    int x = (t >= off) ? s[t - off] : 0;
    __syncthreads();
    s[t] += x;
    __syncthreads();
  }
  if (t < nb) blockoff[t] = s[t] - v;
  if (t == nb - 1) row_start[n] = s[t];
}

__global__ __launch_bounds__(256) void k_scan3(int* __restrict__ row_start, const int* __restrict__ blockoff,
                                               int* __restrict__ fill, int n) {
  int i = blockIdx.x * 256 + threadIdx.x;
  if (i < n) {
    row_start[i] += blockoff[blockIdx.x];
    fill[i] = 0;
  }
}

__global__ void k_scatter(const int* __restrict__ src, const int* __restrict__ dst,
                          const int* __restrict__ row_start, int* __restrict__ fill,
                          int* __restrict__ csr, int e) {
  int i = blockIdx.x * blockDim.x + threadIdx.x;
  if (i < e) {
    int d = dst[i];
    int p = row_start[d] + atomicAdd(&fill[d], 1);
    csr[p] = src[i];
  }
}

// ---------------- fp32 -> packed hi/lo bf16 (MFMA fragment order) ----------------
__global__ void k_cvt_pack(const float* __restrict__ a, ushort* __restrict__ hi,
                           ushort* __restrict__ lo, int total) {
  int i = blockIdx.x * blockDim.x + threadIdx.x;
  if (i >= total) return;
  const float* src = a + (size_t)i * 32;
  ushort h[32], lw[32];
#pragma unroll
  for (int r = 0; r < 32; r++) {
    int p = (r < 16) ? ((r >> 2) * 8 + (r & 3)) : (((r - 16) >> 2) * 8 + 4 + (r & 3));
    float v = src[r];
    ushort hh = f2bf(v);
    h[p] = hh;
    lw[p] = f2bf(v - bf2f(hh));
  }
  ushort* ho = hi + (size_t)i * 32;
  ushort* llo = lo + (size_t)i * 32;
#pragma unroll
  for (int q = 0; q < 4; q++) {
    *(bf16x8*)&ho[q * 8] = *(bf16x8*)&h[q * 8];
    *(bf16x8*)&llo[q * 8] = *(bf16x8*)&lw[q * 8];
  }
}

__global__ void k_prep_w(const float* __restrict__ w, ushort* __restrict__ th,
                         ushort* __restrict__ tl, int K, int OC) {
  int i = blockIdx.x * blockDim.x + threadIdx.x;
  int KC = K / 32;
  if (i >= OC * KC) return;
  int oc = i / KC, c = i % KC;
  ushort h[32], lw[32];
#pragma unroll
  for (int r = 0; r < 32; r++) {
    int p = (r < 16) ? ((r >> 2) * 8 + (r & 3)) : (((r - 16) >> 2) * 8 + 4 + (r & 3));
    float v = w[(size_t)(c * 32 + r) * OC + oc];
    ushort hh = f2bf(v);
    h[p] = hh;
    lw[p] = f2bf(v - bf2f(hh));
  }
  ushort* ho = th + (size_t)oc * K + c * 32;
  ushort* llo = tl + (size_t)oc * K + c * 32;
#pragma unroll
  for (int q = 0; q < 4; q++) {
    *(bf16x8*)&ho[q * 8] = *(bf16x8*)&h[q * 8];
    *(bf16x8*)&llo[q * 8] = *(bf16x8*)&lw[q * 8];
  }
}

// ---------------- MFMA GEMM: async LDS double-buffer, fused asd epilogue ----------------
template <int K, int NCT, int HEADS>
__global__ __launch_bounds__(256) void k_gemm_mfma(const ushort* __restrict__ Ah, const ushort* __restrict__ Al,
                                                   const ushort* __restrict__ Bh, const ushort* __restrict__ Bl,
                                                   const float* __restrict__ asrc, const float* __restrict__ adst,
                                                   _Float16* __restrict__ H, float* __restrict__ a_s,
                                                   float* __restrict__ a_d, int M, int OC) {
  constexpr int BM = 64, BN = NCT * 64, NC = K / 32;
  constexpr int ALO = 2048;
  constexpr int BOFF = 4096;
  constexpr int BLO = BOFF + BN * 32;
  constexpr int BUFE = BOFF + BN * 64;
  __shared__ ushort sb0[BUFE], sb1[BUFE];
  __shared__ float sh_s[4][64], sh_d[4][64];
  int w = threadIdx.x >> 6, l = threadIdx.x & 63;
  int n0 = blockIdx.x * BM;
  int cw = blockIdx.y * BN + w * (NCT * 16);
  int lr = l & 15;

  int q = l & 3;
  int srow = 16 * w + (l >> 2);
  int sgrow = min(n0 + srow, M - 1);
  int gA = q ^ ((srow >> 1) & 3);
  const ushort* aH = Ah + (size_t)sgrow * K + gA * 8;
  const ushort* aL = Al + (size_t)sgrow * K + gA * 8;
  const ushort* bH[NCT];
  const ushort* bL[NCT];
  int colb[NCT];
#pragma unroll
  for (int i = 0; i < NCT; i++) {
    colb[i] = 16 * NCT * w + 16 * i;
    int sc = colb[i] + (l >> 2);
    int gB = q ^ ((sc >> 1) & 3);
    bH[i] = Bh + (size_t)(blockIdx.y * BN + sc) * K + gB * 8;
    bL[i] = Bl + (size_t)(blockIdx.y * BN + sc) * K + gB * 8;
  }

#define STAGE(buf, c)                                              \
  {                                                                \
    gll16(aH + (c) * 32, &buf[0 + w * 512]);                       \
    gll16(aL + (c) * 32, &buf[ALO + w * 512]);                     \
    _Pragma("unroll") for (int i = 0; i < NCT; i++) {              \
      gll16(bH[i] + (c) * 32, &buf[BOFF + colb[i] * 32]);          \
      gll16(bL[i] + (c) * 32, &buf[BLO + colb[i] * 32]);           \
    }                                                              \
  }

  f32x4 acc[4][NCT];
#pragma unroll
  for (int r = 0; r < 4; r++)
#pragma unroll
    for (int t = 0; t < NCT; t++) acc[r][t] = (f32x4){0.f, 0.f, 0.f, 0.f};

#define COMP(buf)                                                                   \
  {                                                                                 \
    bf16x8 bhf[NCT], blf[NCT];                                                      \
    _Pragma("unroll") for (int t = 0; t < NCT; t++) {                               \
      int bcol = 16 * NCT * w + 16 * t + lr;                                        \
      int gb = (l >> 4) ^ ((bcol >> 1) & 3);                                        \
      bhf[t] = *(const bf16x8*)&buf[BOFF + bcol * 32 + gb * 8];                     \
      blf[t] = *(const bf16x8*)&buf[BLO + bcol * 32 + gb * 8];                      \
    }                                                                               \
    _Pragma("unroll") for (int r = 0; r < 4; r++) {                                 \
      int arow = 16 * r + lr;                                                       \
      int ga = (l >> 4) ^ ((arow >> 1) & 3);                                        \
      bf16x8 ahf = *(const bf16x8*)&buf[arow * 32 + ga * 8];                        \
      bf16x8 alf = *(const bf16x8*)&buf[ALO + arow * 32 + ga * 8];                  \
      _Pragma("unroll") for (int t = 0; t < NCT; t++) {                             \
        acc[r][t] = __builtin_amdgcn_mfma_f32_16x16x32_bf16(ahf, bhf[t], acc[r][t], 0, 0, 0); \
        acc[r][t] = __builtin_amdgcn_mfma_f32_16x16x32_bf16(alf, bhf[t], acc[r][t], 0, 0, 0); \
        acc[r][t] = __builtin_amdgcn_mfma_f32_16x16x32_bf16(ahf, blf[t], acc[r][t], 0, 0, 0); \
      }                                                                             \
    }                                                                               \
  }

  ushort* cur = sb0;
  ushort* nxt = sb1;
  STAGE(cur, 0);
  __syncthreads();
  for (int c = 0; c < NC; ++c) {
    if (c + 1 < NC) STAGE(nxt, c + 1);
    COMP(cur);
    __syncthreads();
    ushort* tmp = cur; cur = nxt; nxt = tmp;
  }
#undef STAGE
#undef COMP

#pragma unroll
  for (int r = 0; r < 4; r++)
#pragma unroll
    for (int t = 0; t < NCT; t++)
#pragma unroll
      for (int reg = 0; reg < 4; reg++) {
        int row = n0 + 16 * r + (l >> 4) * 4 + reg;
        if (row < M) H[(size_t)row * OC + cw + 16 * t + lr] = (_Float16)acc[r][t][reg];
      }

  float asv[NCT], adv[NCT];
#pragma unroll
  for (int t = 0; t < NCT; t++) {
    asv[t] = asrc[cw + 16 * t + lr];
    adv[t] = adst[cw + 16 * t + lr];
  }
#pragma unroll
  for (int r = 0; r < 4; r++) {
#pragma unroll
    for (int reg = 0; reg < 4; reg++) {
      float ps = 0.f, pd = 0.f;
#pragma unroll
      for (int t = 0; t < NCT; t++) {
        ps += acc[r][t][reg] * asv[t];
        pd += acc[r][t][reg] * adv[t];
      }
#pragma unroll
      for (int mask = 1; mask < 16; mask <<= 1) {
        ps += __shfl_xor(ps, mask, 64);
        pd += __shfl_xor(pd, mask, 64);
      }
      int rl = 16 * r + (l >> 4) * 4 + reg;
      if (lr == 0) { sh_s[w][rl] = ps; sh_d[w][rl] = pd; }
    }
  }
  __syncthreads();
  int tid = threadIdx.x;
  if (HEADS == 4) {
    if (tid < 128) {
      int rr = tid & 63, hl = tid >> 6;
      int row = n0 + rr;
      if (row < M) {
        int hidx = row * 4 + blockIdx.y * 2 + hl;
        a_s[hidx] = sh_s[2 * hl][rr] + sh_s[2 * hl + 1][rr];
        a_d[hidx] = sh_d[2 * hl][rr] + sh_d[2 * hl + 1][rr];
      }
    }
  } else {
    if (tid < 64) {
      int row = n0 + tid;
      if (row < M) {
        a_s[row] = sh_s[0][tid] + sh_s[1][tid] + sh_s[2][tid] + sh_s[3][tid];
        a_d[row] = sh_d[0][tid] + sh_d[1][tid] + sh_d[2][tid] + sh_d[3][tid];
      }
    }
  }
}

// ---------------- fused softmax + gather-accumulate (4 heads) ----------------
// One wave per node. Phase 1: lanes (head=l>>4, sub=l&15) stride edges for online (m,s).
// Phase 2: all 64 lanes per edge; alpha recomputed from broadcast a_s load (no el buffer).
__global__ __launch_bounds__(256) void k_gat4(const _Float16* __restrict__ h, const float* __restrict__ a_s,
                                              const float* __restrict__ a_d, const int* __restrict__ row_start,
                                              const int* __restrict__ csr, const float* __restrict__ bias,
                                              ushort* __restrict__ Ah, ushort* __restrict__ Al) {
  int wid = threadIdx.x >> 6, l = threadIdx.x & 63;
  int n = blockIdx.x * 4 + wid;
  if (n >= NNODES) return;
  int head = l >> 4, sub = l & 15;
  int jb = row_start[n], je = row_start[n + 1];
  float ad = a_d[n * 4 + head];
  float es = leaky(a_s[n * 4 + head] + ad);
  float m = -1e30f, s = 0.f;
  if (sub == 0) { m = es; s = 1.f; }
  for (int j = jb + sub; j < je; j += 16) {
    float e = leaky(a_s[csr[j] * 4 + head] + ad);
    float nm = fmaxf(m, e);
    s = s * __expf(m - nm) + __expf(e - nm);
    m = nm;
  }
#pragma unroll
  for (int mask = 1; mask < 16; mask <<= 1) {
    float m2 = __shfl_xor(m, mask, 64);
    float s2 = __shfl_xor(s, mask, 64);
    float nm = fmaxf(m, m2);
    s = s * __expf(m - nm) + s2 * __expf(m2 - nm);
    m = nm;
  }
  float inv = 1.f / s;
  float sa = __expf(es - m) * inv;
  f16x4 hv = *(const f16x4*)&h[(size_t)n * 256 + l * 4];
  float4 acc = {sa * (float)hv[0], sa * (float)hv[1], sa * (float)hv[2], sa * (float)hv[3]};
  int j = jb;
  for (; j + 3 < je; j += 4) {
    int s0 = csr[j], s1 = csr[j + 1], s2 = csr[j + 2], s3 = csr[j + 3];
    float a0 = __expf(leaky(a_s[s0 * 4 + head] + ad) - m) * inv;
    float a1 = __expf(leaky(a_s[s1 * 4 + head] + ad) - m) * inv;
    float a2 = __expf(leaky(a_s[s2 * 4 + head] + ad) - m) * inv;
    float a3 = __expf(leaky(a_s[s3 * 4 + head] + ad) - m) * inv;
    f16x4 v0 = *(const f16x4*)&h[(size_t)s0 * 256 + l * 4];
    f16x4 v1 = *(const f16x4*)&h[(size_t)s1 * 256 + l * 4];
    f16x4 v2 = *(const f16x4*)&h[(size_t)s2 * 256 + l * 4];
    f16x4 v3 = *(const f16x4*)&h[(size_t)s3 * 256 + l * 4];
    acc.x += a0 * (float)v0[0] + a1 * (float)v1[0] + a2 * (float)v2[0] + a3 * (float)v3[0];
    acc.y += a0 * (float)v0[1] + a1 * (float)v1[1] + a2 * (float)v2[1] + a3 * (float)v3[1];
    acc.z += a0 * (float)v0[2] + a1 * (float)v1[2] + a2 * (float)v2[2] + a3 * (float)v3[2];
    acc.w += a0 * (float)v0[3] + a1 * (float)v1[3] + a2 * (float)v2[3] + a3 * (float)v3[3];
  }
  for (; j < je; j++) {
    int s0 = csr[j];
    float a0 = __expf(leaky(a_s[s0 * 4 + head] + ad) - m) * inv;
    f16x4 v0 = *(const f16x4*)&h[(size_t)s0 * 256 + l * 4];
    acc.x += a0 * (float)v0[0]; acc.y += a0 * (float)v0[1];
    acc.z += a0 * (float)v0[2]; acc.w += a0 * (float)v0[3];
  }
  float4 b = *(const float4*)&bias[l * 4];
  float4 o;
  o.x = elu(acc.x + b.x); o.y = elu(acc.y + b.y);
  o.z = elu(acc.z + b.z); o.w = elu(acc.w + b.w);
  size_t base = (size_t)n * 256 + (l >> 3) * 32 + (l & 3) * 8 + (((l & 7) >= 4) ? 4 : 0);
  ushort4 hh, ll;
  hh.x = f2bf(o.x); ll.x = f2bf(o.x - bf2f(hh.x));
  hh.y = f2bf(o.y); ll.y = f2bf(o.y - bf2f(hh.y));
  hh.z = f2bf(o.z); ll.z = f2bf(o.z - bf2f(hh.z));
  hh.w = f2bf(o.w); ll.w = f2bf(o.w - bf2f(hh.w));
  *(ushort4*)&Ah[base] = hh;
  *(ushort4*)&Al[base] = ll;
}

// ---------------- fused softmax + gather + MLP (1 head) ----------------
__global__ __launch_bounds__(256) void k_gat1(const _Float16* __restrict__ h, const float* __restrict__ a_s,
                                              const float* __restrict__ a_d, const int* __restrict__ row_start,
                                              const int* __restrict__ csr, const float* __restrict__ bias,
                                              const float* __restrict__ w1, const float* __restrict__ b1,
                                              const float* __restrict__ w2, const float* __restrict__ b2,
                                              float* __restrict__ out) {
  __shared__ float sh[4][64];
  int wid = threadIdx.x >> 6, l = threadIdx.x & 63;
  int n = blockIdx.x * 4 + wid;
  float val = 0.f;
  if (n < NNODES) {
    int jb = row_start[n], je = row_start[n + 1];
    float ad = a_d[n];
    float es = leaky(a_s[n] + ad);
    float m = -1e30f, s = 0.f;
    if (l == 0) { m = es; s = 1.f; }
    for (int j = jb + l; j < je; j += 64) {
      float e = leaky(a_s[csr[j]] + ad);
      float nm = fmaxf(m, e);
      s = s * __expf(m - nm) + __expf(e - nm);
      m = nm;
    }
#pragma unroll
    for (int mask = 1; mask < 64; mask <<= 1) {
      float m2 = __shfl_xor(m, mask, 64);
      float s2 = __shfl_xor(s, mask, 64);
      float nm = fmaxf(m, m2);
      s = s * __expf(m - nm) + s2 * __expf(m2 - nm);
      m = nm;
    }
    float inv = 1.f / s;
    float acc = __expf(es - m) * inv * (float)h[(size_t)n * 64 + l];
    int j = jb;
    for (; j + 3 < je; j += 4) {
      int s0 = csr[j], s1 = csr[j + 1], s2 = csr[j + 2], s3 = csr[j + 3];
      float a0 = __expf(leaky(a_s[s0] + ad) - m) * inv;
      float a1 = __expf(leaky(a_s[s1] + ad) - m) * inv;
      float a2 = __expf(leaky(a_s[s2] + ad) - m) * inv;
      float a3 = __expf(leaky(a_s[s3] + ad) - m) * inv;
      float v0 = (float)h[(size_t)s0 * 64 + l];
      float v1 = (float)h[(size_t)s1 * 64 + l];
      float v2 = (float)h[(size_t)s2 * 64 + l];
      float v3 = (float)h[(size_t)s3 * 64 + l];
      acc += a0 * v0 + a1 * v1 + a2 * v2 + a3 * v3;
    }
    for (; j < je; j++)
      acc += __expf(leaky(a_s[csr[j]] + ad) - m) * inv * (float)h[(size_t)csr[j] * 64 + l];
    val = elu(acc + bias[l]);
  }
  sh[wid][l] = val;
  __syncthreads();
  float r = 0.f;
  if (l < 32 && n < NNODES) {
    r = b1[l];
#pragma unroll 8
    for (int k = 0; k < 64; k++) r += sh[wid][k] * w1[k * 32 + l];
    r = fmaxf(r, 0.f);
    r *= w2[l];
  }
  for (int mask = 16; mask >= 1; mask >>= 1) r += __shfl_xor(r, mask, 64);
  if (l == 0 && n < NNODES) out[n] = r + b2[0];
}

extern "C" void kernel_launch(void* const* d_in, const int* in_sizes, int n_in,
                              void* d_out, int out_size, void* d_ws, size_t ws_size,
                              hipStream_t stream) {
  const float* x    = (const float*)d_in[0];
  const int*   eidx = (const int*)d_in[1];
  const float* lin0 = (const float*)d_in[2];
  const float* as0  = (const float*)d_in[3];
  const float* ad0  = (const float*)d_in[4];
  const float* b0   = (const float*)d_in[5];
  const float* lin1 = (const float*)d_in[6];
  const float* as1  = (const float*)d_in[7];
  const float* ad1  = (const float*)d_in[8];
  const float* b1l  = (const float*)d_in[9];
  const float* lin2 = (const float*)d_in[10];
  const float* as2  = (const float*)d_in[11];
  const float* ad2  = (const float*)d_in[12];
  const float* b2l  = (const float*)d_in[13];
  const float* w1   = (const float*)d_in[14];
  const float* mb1  = (const float*)d_in[15];
  const float* w2   = (const float*)d_in[16];
  const float* mb2  = (const float*)d_in[17];
  float* outp = (float*)d_out;

  const int* srcA = eidx;
  const int* dstA = eidx + NEDGES;

  char* ws = (char*)d_ws;
  size_t o = 0;
  auto alloc = [&](size_t bytes) { size_t r = o; o += (bytes + 255) & ~255UL; return r; };
  _Float16* h16 = (_Float16*)(ws + alloc((size_t)NNODES * 256 * 2));
  ushort* Ahp = (ushort*)(ws + alloc((size_t)NNODES * 256 * 2));
  ushort* Alp = (ushort*)(ws + alloc((size_t)NNODES * 256 * 2));
  ushort* wh  = (ushort*)(ws + alloc(256 * 256 * 2));
  ushort* wl  = (ushort*)(ws + alloc(256 * 256 * 2));
  float*  vas = (float*)(ws + alloc((size_t)NNODES * 4 * 4));
  float*  vad = (float*)(ws + alloc((size_t)NNODES * 4 * 4));
  int* row_start = (int*)(ws + alloc((NNODES + 1) * 4));
  int* fill      = (int*)(ws + alloc(NNODES * 4));
  int* csr       = (int*)(ws + alloc(NEDGES * 4));
  int* blocksum  = (int*)(ws + alloc(SCAN_NB * 4));
  int* blockoff  = (int*)(ws + alloc(SCAN_NB * 4));

  // Build dst-sorted CSR (self-loops handled implicitly)
  k_zero<<<(NNODES + 255) / 256, 256, 0, stream>>>(fill, NNODES);
  k_hist<<<(NEDGES + 255) / 256, 256, 0, stream>>>(dstA, fill, NEDGES);
  k_scan1<<<SCAN_NB, 256, 0, stream>>>(fill, row_start, blocksum, NNODES);
  k_scan2<<<1, 128, 0, stream>>>(blocksum, blockoff, row_start, SCAN_NB, NNODES);
  k_scan3<<<SCAN_NB, 256, 0, stream>>>(row_start, blockoff, fill, NNODES);
  k_scatter<<<(NEDGES + 255) / 256, 256, 0, stream>>>(srcA, dstA, row_start, fill, csr, NEDGES);

  dim3 g44((NNODES + 63) / 64, 2);   // 4-head GEMMs: BM=64, BN=128
  dim3 g21((NNODES + 63) / 64, 1);   // 1-head GEMM:  BM=64, BN=64

  // ---- layer 0 (IN=128 -> 4x64, concat) ----
  k_cvt_pack<<<(NNODES * 4 + 255) / 256, 256, 0, stream>>>(x, Ahp, Alp, NNODES * 4);
  k_prep_w<<<(256 * 4 + 255) / 256, 256, 0, stream>>>(lin0, wh, wl, 128, 256);
  k_gemm_mfma<128, 2, 4><<<g44, 256, 0, stream>>>(Ahp, Alp, wh, wl, as0, ad0, h16, vas, vad, NNODES, 256);
  k_gat4<<<5000, 256, 0, stream>>>(h16, vas, vad, row_start, csr, b0, Ahp, Alp);

  // ---- layer 1 (256 -> 4x64, concat) ----
  k_prep_w<<<(256 * 8 + 255) / 256, 256, 0, stream>>>(lin1, wh, wl, 256, 256);
  k_gemm_mfma<256, 2, 4><<<g44, 256, 0, stream>>>(Ahp, Alp, wh, wl, as1, ad1, h16, vas, vad, NNODES, 256);
  k_gat4<<<5000, 256, 0, stream>>>(h16, vas, vad, row_start, csr, b1l, Ahp, Alp);

  // ---- layer 2 (256 -> 64, 1 head, mean) + MLP ----
  k_prep_w<<<(64 * 8 + 255) / 256, 256, 0, stream>>>(lin2, wh, wl, 256, 64);
  k_gemm_mfma<256, 1, 1><<<g21, 256, 0, stream>>>(Ahp, Alp, wh, wl, as2, ad2, h16, vas, vad, NNODES, 64);
  k_gat1<<<5000, 256, 0, stream>>>(h16, vas, vad, row_start, csr, b2l, w1, mb1, w2, mb2, outp);
}

// Round 10
// 193.909 us; speedup vs baseline: 1.3526x; 1.0784x over previous
//
#include <hip/hip_runtime.h>

#define NNODES 20000
#define NEDGES 320000
#define SCAN_NB ((NNODES + 255) / 256)   // 79
#define DCAP 120                          // per-node cached-logit cap (mean deg 16)

typedef __attribute__((ext_vector_type(8))) short bf16x8;
typedef __attribute__((ext_vector_type(4))) float f32x4;
typedef _Float16 f16x4 __attribute__((ext_vector_type(4)));

__device__ __forceinline__ float leaky(float x) { return x > 0.f ? x : 0.2f * x; }
__device__ __forceinline__ float elu(float x) { return x > 0.f ? x : expm1f(x); }

__device__ __forceinline__ ushort f2bf(float f) {
  uint u = __float_as_uint(f);
  uint r = (u + 0x7fffu + ((u >> 16) & 1u)) >> 16;
  return (ushort)r;
}
__device__ __forceinline__ float bf2f(ushort h) {
  return __uint_as_float(((uint)h) << 16);
}

// async 16B global->LDS (DMA; zero VGPR cost; compiler cannot serialize it)
__device__ __forceinline__ void gll16(const ushort* g, ushort* l) {
  __builtin_amdgcn_global_load_lds((const __attribute__((address_space(1))) void*)g,
                                   (__attribute__((address_space(3))) void*)l, 16, 0, 0);
}

// ---------------- CSR build ----------------
__global__ void k_zero(int* __restrict__ p, int n) {
  int i = blockIdx.x * blockDim.x + threadIdx.x;
  if (i < n) p[i] = 0;
}

__global__ void k_hist(const int* __restrict__ dst, int* __restrict__ cnt, int e) {
  int i = blockIdx.x * blockDim.x + threadIdx.x;
  if (i < e) atomicAdd(&cnt[dst[i]], 1);
}

__global__ __launch_bounds__(256) void k_scan1(const int* __restrict__ cnt, int* __restrict__ row_start,
                                               int* __restrict__ blocksum, int n) {
  __shared__ int s[256];
  int t = threadIdx.x;
  int i = blockIdx.x * 256 + t;
  int v = (i < n) ? cnt[i] : 0;
  s[t] = v;
  __syncthreads();
  for (int off = 1; off < 256; off <<= 1) {
    int x = (t >= off) ? s[t - off] : 0;
    __syncthreads();
    s[t] += x;
    __syncthreads();
  }
  if (i < n) row_start[i] = s[t] - v;
  if (t == 255) blocksum[blockIdx.x] = s[255];
}

__global__ __launch_bounds__(128) void k_scan2(int* __restrict__ blocksum, int* __restrict__ blockoff,
                                               int* __restrict__ row_start, int nb, int n) {
  __shared__ int s[128];
  int t = threadIdx.x;
  int v = (t < nb) ? blocksum[t] : 0;
  s[t] = v;
  __syncthreads();
  for (int off = 1; off < 128; off <<= 1) {
    int x = (t >= off) ? s[t - off] : 0;
    __syncthreads();
    s[t] += x;
    __syncthreads();
  }
  if (t < nb) blockoff[t] = s[t] - v;
  if (t == nb - 1) row_start[n] = s[t];
}

__global__ __launch_bounds__(256) void k_scan3(int* __restrict__ row_start, const int* __restrict__ blockoff,
                                               int* __restrict__ fill, int n) {
  int i = blockIdx.x * 256 + threadIdx.x;
  if (i < n) {
    row_start[i] += blockoff[blockIdx.x];
    fill[i] = 0;
  }
}

__global__ void k_scatter(const int* __restrict__ src, const int* __restrict__ dst,
                          const int* __restrict__ row_start, int* __restrict__ fill,
                          int* __restrict__ csr, int e) {
  int i = blockIdx.x * blockDim.x + threadIdx.x;
  if (i < e) {
    int d = dst[i];
    int p = row_start[d] + atomicAdd(&fill[d], 1);
    csr[p] = src[i];
  }
}

// ---------------- fp32 -> packed hi/lo bf16 (MFMA fragment order) ----------------
__global__ void k_cvt_pack(const float* __restrict__ a, ushort* __restrict__ hi,
                           ushort* __restrict__ lo, int total) {
  int i = blockIdx.x * blockDim.x + threadIdx.x;
  if (i >= total) return;
  const float* src = a + (size_t)i * 32;
  ushort h[32], lw[32];
#pragma unroll
  for (int r = 0; r < 32; r++) {
    int p = (r < 16) ? ((r >> 2) * 8 + (r & 3)) : (((r - 16) >> 2) * 8 + 4 + (r & 3));
    float v = src[r];
    ushort hh = f2bf(v);
    h[p] = hh;
    lw[p] = f2bf(v - bf2f(hh));
  }
  ushort* ho = hi + (size_t)i * 32;
  ushort* llo = lo + (size_t)i * 32;
#pragma unroll
  for (int q = 0; q < 4; q++) {
    *(bf16x8*)&ho[q * 8] = *(bf16x8*)&h[q * 8];
    *(bf16x8*)&llo[q * 8] = *(bf16x8*)&lw[q * 8];
  }
}

// all three weight matrices in one dispatch
__device__ __forceinline__ void prep_w_one(const float* __restrict__ w, ushort* __restrict__ th,
                                           ushort* __restrict__ tl, int K, int OC, int idx) {
  int KC = K / 32;
  int oc = idx / KC, c = idx % KC;
  ushort h[32], lw[32];
#pragma unroll
  for (int r = 0; r < 32; r++) {
    int p = (r < 16) ? ((r >> 2) * 8 + (r & 3)) : (((r - 16) >> 2) * 8 + 4 + (r & 3));
    float v = w[(size_t)(c * 32 + r) * OC + oc];
    ushort hh = f2bf(v);
    h[p] = hh;
    lw[p] = f2bf(v - bf2f(hh));
  }
  ushort* ho = th + (size_t)oc * K + c * 32;
  ushort* llo = tl + (size_t)oc * K + c * 32;
#pragma unroll
  for (int q = 0; q < 4; q++) {
    *(bf16x8*)&ho[q * 8] = *(bf16x8*)&h[q * 8];
    *(bf16x8*)&llo[q * 8] = *(bf16x8*)&lw[q * 8];
  }
}

__global__ void k_prep_w3(const float* __restrict__ w0, const float* __restrict__ w1,
                          const float* __restrict__ w2,
                          ushort* __restrict__ th0, ushort* __restrict__ tl0,
                          ushort* __restrict__ th1, ushort* __restrict__ tl1,
                          ushort* __restrict__ th2, ushort* __restrict__ tl2) {
  int i = blockIdx.x * blockDim.x + threadIdx.x;
  if (i < 1024) prep_w_one(w0, th0, tl0, 128, 256, i);                 // 256*4
  else if (i < 3072) prep_w_one(w1, th1, tl1, 256, 256, i - 1024);     // 256*8
  else if (i < 3584) prep_w_one(w2, th2, tl2, 256, 64, i - 3072);      // 64*8
}

// ---------------- MFMA GEMM: async LDS double-buffer, fused asd epilogue ----------------
template <int K, int NCT, int HEADS>
__global__ __launch_bounds__(256) void k_gemm_mfma(const ushort* __restrict__ Ah, const ushort* __restrict__ Al,
                                                   const ushort* __restrict__ Bh, const ushort* __restrict__ Bl,
                                                   const float* __restrict__ asrc, const float* __restrict__ adst,
                                                   _Float16* __restrict__ H, float* __restrict__ a_s,
                                                   float* __restrict__ a_d, int M, int OC) {
  constexpr int BM = 64, BN = NCT * 64, NC = K / 32;
  constexpr int ALO = 2048;
  constexpr int BOFF = 4096;
  constexpr int BLO = BOFF + BN * 32;
  constexpr int BUFE = BOFF + BN * 64;
  __shared__ ushort sb0[BUFE], sb1[BUFE];
  __shared__ float sh_s[4][64], sh_d[4][64];
  int w = threadIdx.x >> 6, l = threadIdx.x & 63;
  int n0 = blockIdx.x * BM;
  int cw = blockIdx.y * BN + w * (NCT * 16);
  int lr = l & 15;

  int q = l & 3;
  int srow = 16 * w + (l >> 2);
  int sgrow = min(n0 + srow, M - 1);
  int gA = q ^ ((srow >> 1) & 3);
  const ushort* aH = Ah + (size_t)sgrow * K + gA * 8;
  const ushort* aL = Al + (size_t)sgrow * K + gA * 8;
  const ushort* bH[NCT];
  const ushort* bL[NCT];
  int colb[NCT];
#pragma unroll
  for (int i = 0; i < NCT; i++) {
    colb[i] = 16 * NCT * w + 16 * i;
    int sc = colb[i] + (l >> 2);
    int gB = q ^ ((sc >> 1) & 3);
    bH[i] = Bh + (size_t)(blockIdx.y * BN + sc) * K + gB * 8;
    bL[i] = Bl + (size_t)(blockIdx.y * BN + sc) * K + gB * 8;
  }

#define STAGE(buf, c)                                              \
  {                                                                \
    gll16(aH + (c) * 32, &buf[0 + w * 512]);                       \
    gll16(aL + (c) * 32, &buf[ALO + w * 512]);                     \
    _Pragma("unroll") for (int i = 0; i < NCT; i++) {              \
      gll16(bH[i] + (c) * 32, &buf[BOFF + colb[i] * 32]);          \
      gll16(bL[i] + (c) * 32, &buf[BLO + colb[i] * 32]);           \
    }                                                              \
  }

  f32x4 acc[4][NCT];
#pragma unroll
  for (int r = 0; r < 4; r++)
#pragma unroll
    for (int t = 0; t < NCT; t++) acc[r][t] = (f32x4){0.f, 0.f, 0.f, 0.f};

#define COMP(buf)                                                                   \
  {                                                                                 \
    bf16x8 bhf[NCT], blf[NCT];                                                      \
    _Pragma("unroll") for (int t = 0; t < NCT; t++) {                               \
      int bcol = 16 * NCT * w + 16 * t + lr;                                        \
      int gb = (l >> 4) ^ ((bcol >> 1) & 3);                                        \
      bhf[t] = *(const bf16x8*)&buf[BOFF + bcol * 32 + gb * 8];                     \
      blf[t] = *(const bf16x8*)&buf[BLO + bcol * 32 + gb * 8];                      \
    }                                                                               \
    _Pragma("unroll") for (int r = 0; r < 4; r++) {                                 \
      int arow = 16 * r + lr;                                                       \
      int ga = (l >> 4) ^ ((arow >> 1) & 3);                                        \
      bf16x8 ahf = *(const bf16x8*)&buf[arow * 32 + ga * 8];                        \
      bf16x8 alf = *(const bf16x8*)&buf[ALO + arow * 32 + ga * 8];                  \
      _Pragma("unroll") for (int t = 0; t < NCT; t++) {                             \
        acc[r][t] = __builtin_amdgcn_mfma_f32_16x16x32_bf16(ahf, bhf[t], acc[r][t], 0, 0, 0); \
        acc[r][t] = __builtin_amdgcn_mfma_f32_16x16x32_bf16(alf, bhf[t], acc[r][t], 0, 0, 0); \
        acc[r][t] = __builtin_amdgcn_mfma_f32_16x16x32_bf16(ahf, blf[t], acc[r][t], 0, 0, 0); \
      }                                                                             \
    }                                                                               \
  }

  ushort* cur = sb0;
  ushort* nxt = sb1;
  STAGE(cur, 0);
  __syncthreads();
  for (int c = 0; c < NC; ++c) {
    if (c + 1 < NC) STAGE(nxt, c + 1);
    COMP(cur);
    __syncthreads();
    ushort* tmp = cur; cur = nxt; nxt = tmp;
  }
#undef STAGE
#undef COMP

#pragma unroll
  for (int r = 0; r < 4; r++)
#pragma unroll
    for (int t = 0; t < NCT; t++)
#pragma unroll
      for (int reg = 0; reg < 4; reg++) {
        int row = n0 + 16 * r + (l >> 4) * 4 + reg;
        if (row < M) H[(size_t)row * OC + cw + 16 * t + lr] = (_Float16)acc[r][t][reg];
      }

  float asv[NCT], adv[NCT];
#pragma unroll
  for (int t = 0; t < NCT; t++) {
    asv[t] = asrc[cw + 16 * t + lr];
    adv[t] = adst[cw + 16 * t + lr];
  }
#pragma unroll
  for (int r = 0; r < 4; r++) {
#pragma unroll
    for (int reg = 0; reg < 4; reg++) {
      float ps = 0.f, pd = 0.f;
#pragma unroll
      for (int t = 0; t < NCT; t++) {
        ps += acc[r][t][reg] * asv[t];
        pd += acc[r][t][reg] * adv[t];
      }
#pragma unroll
      for (int mask = 1; mask < 16; mask <<= 1) {
        ps += __shfl_xor(ps, mask, 64);
        pd += __shfl_xor(pd, mask, 64);
      }
      int rl = 16 * r + (l >> 4) * 4 + reg;
      if (lr == 0) { sh_s[w][rl] = ps; sh_d[w][rl] = pd; }
    }
  }
  __syncthreads();
  int tid = threadIdx.x;
  if (HEADS == 4) {
    if (tid < 128) {
      int rr = tid & 63, hl = tid >> 6;
      int row = n0 + rr;
      if (row < M) {
        int hidx = row * 4 + blockIdx.y * 2 + hl;
        a_s[hidx] = sh_s[2 * hl][rr] + sh_s[2 * hl + 1][rr];
        a_d[hidx] = sh_d[2 * hl][rr] + sh_d[2 * hl + 1][rr];
      }
    }
  } else {
    if (tid < 64) {
      int row = n0 + tid;
      if (row < M) {
        a_s[row] = sh_s[0][tid] + sh_s[1][tid] + sh_s[2][tid] + sh_s[3][tid];
        a_d[row] = sh_d[0][tid] + sh_d[1][tid] + sh_d[2][tid] + sh_d[3][tid];
      }
    }
  }
}

// ---------------- fused softmax + gather-accumulate (4 heads), LDS logit cache ----------------
// One wave per node. Phase 1 computes logits once (gather a_s) and caches them in LDS;
// phase 2 reads alpha via broadcast LDS read (free) -> one global gather (h) per edge.
__global__ __launch_bounds__(256) void k_gat4(const _Float16* __restrict__ h, const float* __restrict__ a_s,
                                              const float* __restrict__ a_d, const int* __restrict__ row_start,
                                              const int* __restrict__ csr, const float* __restrict__ bias,
                                              ushort* __restrict__ Ah, ushort* __restrict__ Al) {
  __shared__ float elds[4][DCAP * 4];
  int wid = threadIdx.x >> 6, l = threadIdx.x & 63;
  int n = blockIdx.x * 4 + wid;
  if (n >= NNODES) return;
  int head = l >> 4, sub = l & 15;
  int jb = row_start[n], je = row_start[n + 1];
  float ad = a_d[n * 4 + head];
  float es = leaky(a_s[n * 4 + head] + ad);
  float m = -1e30f, s = 0.f;
  if (sub == 0) { m = es; s = 1.f; }
  for (int j = jb + sub; j < je; j += 16) {
    float e = leaky(a_s[csr[j] * 4 + head] + ad);
    int o = j - jb;
    if (o < DCAP) elds[wid][o * 4 + head] = e;
    float nm = fmaxf(m, e);
    s = s * __expf(m - nm) + __expf(e - nm);
    m = nm;
  }
#pragma unroll
  for (int mask = 1; mask < 16; mask <<= 1) {
    float m2 = __shfl_xor(m, mask, 64);
    float s2 = __shfl_xor(s, mask, 64);
    float nm = fmaxf(m, m2);
    s = s * __expf(m - nm) + s2 * __expf(m2 - nm);
    m = nm;
  }
  __asm__ volatile("" ::: "memory");   // keep LDS writes ordered before reads (same wave)
  float inv = 1.f / s;
  float sa = __expf(es - m) * inv;
  f16x4 hv = *(const f16x4*)&h[(size_t)n * 256 + l * 4];
  float4 acc = {sa * (float)hv[0], sa * (float)hv[1], sa * (float)hv[2], sa * (float)hv[3]};
  int jcap = min(je, jb + DCAP);
  int j = jb;
  for (; j + 3 < jcap; j += 4) {
    int o = j - jb;
    int s0 = csr[j], s1 = csr[j + 1], s2 = csr[j + 2], s3 = csr[j + 3];
    float a0 = __expf(elds[wid][(o + 0) * 4 + head] - m) * inv;
    float a1 = __expf(elds[wid][(o + 1) * 4 + head] - m) * inv;
    float a2 = __expf(elds[wid][(o + 2) * 4 + head] - m) * inv;
    float a3 = __expf(elds[wid][(o + 3) * 4 + head] - m) * inv;
    f16x4 v0 = *(const f16x4*)&h[(size_t)s0 * 256 + l * 4];
    f16x4 v1 = *(const f16x4*)&h[(size_t)s1 * 256 + l * 4];
    f16x4 v2 = *(const f16x4*)&h[(size_t)s2 * 256 + l * 4];
    f16x4 v3 = *(const f16x4*)&h[(size_t)s3 * 256 + l * 4];
    acc.x += a0 * (float)v0[0] + a1 * (float)v1[0] + a2 * (float)v2[0] + a3 * (float)v3[0];
    acc.y += a0 * (float)v0[1] + a1 * (float)v1[1] + a2 * (float)v2[1] + a3 * (float)v3[1];
    acc.z += a0 * (float)v0[2] + a1 * (float)v1[2] + a2 * (float)v2[2] + a3 * (float)v3[2];
    acc.w += a0 * (float)v0[3] + a1 * (float)v1[3] + a2 * (float)v2[3] + a3 * (float)v3[3];
  }
  for (; j < jcap; j++) {
    int s0 = csr[j];
    float a0 = __expf(elds[wid][(j - jb) * 4 + head] - m) * inv;
    f16x4 v0 = *(const f16x4*)&h[(size_t)s0 * 256 + l * 4];
    acc.x += a0 * (float)v0[0]; acc.y += a0 * (float)v0[1];
    acc.z += a0 * (float)v0[2]; acc.w += a0 * (float)v0[3];
  }
  for (; j < je; j++) {   // overflow fallback (deg > DCAP)
    int s0 = csr[j];
    float a0 = __expf(leaky(a_s[s0 * 4 + head] + ad) - m) * inv;
    f16x4 v0 = *(const f16x4*)&h[(size_t)s0 * 256 + l * 4];
    acc.x += a0 * (float)v0[0]; acc.y += a0 * (float)v0[1];
    acc.z += a0 * (float)v0[2]; acc.w += a0 * (float)v0[3];
  }
  float4 b = *(const float4*)&bias[l * 4];
  float4 o;
  o.x = elu(acc.x + b.x); o.y = elu(acc.y + b.y);
  o.z = elu(acc.z + b.z); o.w = elu(acc.w + b.w);
  size_t base = (size_t)n * 256 + (l >> 3) * 32 + (l & 3) * 8 + (((l & 7) >= 4) ? 4 : 0);
  ushort4 hh, ll;
  hh.x = f2bf(o.x); ll.x = f2bf(o.x - bf2f(hh.x));
  hh.y = f2bf(o.y); ll.y = f2bf(o.y - bf2f(hh.y));
  hh.z = f2bf(o.z); ll.z = f2bf(o.z - bf2f(hh.z));
  hh.w = f2bf(o.w); ll.w = f2bf(o.w - bf2f(hh.w));
  *(ushort4*)&Ah[base] = hh;
  *(ushort4*)&Al[base] = ll;
}

// ---------------- fused softmax + gather + MLP (1 head), LDS logit cache ----------------
__global__ __launch_bounds__(256) void k_gat1(const _Float16* __restrict__ h, const float* __restrict__ a_s,
                                              const float* __restrict__ a_d, const int* __restrict__ row_start,
                                              const int* __restrict__ csr, const float* __restrict__ bias,
                                              const float* __restrict__ w1, const float* __restrict__ b1,
                                              const float* __restrict__ w2, const float* __restrict__ b2,
                                              float* __restrict__ out) {
  __shared__ float elds[4][DCAP];
  __shared__ float sh[4][64];
  int wid = threadIdx.x >> 6, l = threadIdx.x & 63;
  int n = blockIdx.x * 4 + wid;
  float val = 0.f;
  if (n < NNODES) {
    int jb = row_start[n], je = row_start[n + 1];
    float ad = a_d[n];
    float es = leaky(a_s[n] + ad);
    float m = -1e30f, s = 0.f;
    if (l == 0) { m = es; s = 1.f; }
    for (int j = jb + l; j < je; j += 64) {
      float e = leaky(a_s[csr[j]] + ad);
      int o = j - jb;
      if (o < DCAP) elds[wid][o] = e;
      float nm = fmaxf(m, e);
      s = s * __expf(m - nm) + __expf(e - nm);
      m = nm;
    }
#pragma unroll
    for (int mask = 1; mask < 64; mask <<= 1) {
      float m2 = __shfl_xor(m, mask, 64);
      float s2 = __shfl_xor(s, mask, 64);
      float nm = fmaxf(m, m2);
      s = s * __expf(m - nm) + s2 * __expf(m2 - nm);
      m = nm;
    }
    __asm__ volatile("" ::: "memory");
    float inv = 1.f / s;
    float acc = __expf(es - m) * inv * (float)h[(size_t)n * 64 + l];
    int jcap = min(je, jb + DCAP);
    int j = jb;
    for (; j + 3 < jcap; j += 4) {
      int o = j - jb;
      int s0 = csr[j], s1 = csr[j + 1], s2 = csr[j + 2], s3 = csr[j + 3];
      float a0 = __expf(elds[wid][o + 0] - m) * inv;
      float a1 = __expf(elds[wid][o + 1] - m) * inv;
      float a2 = __expf(elds[wid][o + 2] - m) * inv;
      float a3 = __expf(elds[wid][o + 3] - m) * inv;
      float v0 = (float)h[(size_t)s0 * 64 + l];
      float v1 = (float)h[(size_t)s1 * 64 + l];
      float v2 = (float)h[(size_t)s2 * 64 + l];
      float v3 = (float)h[(size_t)s3 * 64 + l];
      acc += a0 * v0 + a1 * v1 + a2 * v2 + a3 * v3;
    }
    for (; j < jcap; j++)
      acc += __expf(elds[wid][j - jb] - m) * inv * (float)h[(size_t)csr[j] * 64 + l];
    for (; j < je; j++)
      acc += __expf(leaky(a_s[csr[j]] + ad) - m) * inv * (float)h[(size_t)csr[j] * 64 + l];
    val = elu(acc + bias[l]);
  }
  sh[wid][l] = val;
  __syncthreads();
  float r = 0.f;
  if (l < 32 && n < NNODES) {
    r = b1[l];
#pragma unroll 8
    for (int k = 0; k < 64; k++) r += sh[wid][k] * w1[k * 32 + l];
    r = fmaxf(r, 0.f);
    r *= w2[l];
  }
  for (int mask = 16; mask >= 1; mask >>= 1) r += __shfl_xor(r, mask, 64);
  if (l == 0 && n < NNODES) out[n] = r + b2[0];
}

extern "C" void kernel_launch(void* const* d_in, const int* in_sizes, int n_in,
                              void* d_out, int out_size, void* d_ws, size_t ws_size,
                              hipStream_t stream) {
  const float* x    = (const float*)d_in[0];
  const int*   eidx = (const int*)d_in[1];
  const float* lin0 = (const float*)d_in[2];
  const float* as0  = (const float*)d_in[3];
  const float* ad0  = (const float*)d_in[4];
  const float* b0   = (const float*)d_in[5];
  const float* lin1 = (const float*)d_in[6];
  const float* as1  = (const float*)d_in[7];
  const float* ad1  = (const float*)d_in[8];
  const float* b1l  = (const float*)d_in[9];
  const float* lin2 = (const float*)d_in[10];
  const float* as2  = (const float*)d_in[11];
  const float* ad2  = (const float*)d_in[12];
  const float* b2l  = (const float*)d_in[13];
  const float* w1   = (const float*)d_in[14];
  const float* mb1  = (const float*)d_in[15];
  const float* w2   = (const float*)d_in[16];
  const float* mb2  = (const float*)d_in[17];
  float* outp = (float*)d_out;

  const int* srcA = eidx;
  const int* dstA = eidx + NEDGES;

  char* ws = (char*)d_ws;
  size_t o = 0;
  auto alloc = [&](size_t bytes) { size_t r = o; o += (bytes + 255) & ~255UL; return r; };
  _Float16* h16 = (_Float16*)(ws + alloc((size_t)NNODES * 256 * 2));
  ushort* Ahp = (ushort*)(ws + alloc((size_t)NNODES * 256 * 2));
  ushort* Alp = (ushort*)(ws + alloc((size_t)NNODES * 256 * 2));
  ushort* wh0 = (ushort*)(ws + alloc(128 * 256 * 2));
  ushort* wl0 = (ushort*)(ws + alloc(128 * 256 * 2));
  ushort* wh1 = (ushort*)(ws + alloc(256 * 256 * 2));
  ushort* wl1 = (ushort*)(ws + alloc(256 * 256 * 2));
  ushort* wh2 = (ushort*)(ws + alloc(256 * 64 * 2));
  ushort* wl2 = (ushort*)(ws + alloc(256 * 64 * 2));
  float*  vas = (float*)(ws + alloc((size_t)NNODES * 4 * 4));
  float*  vad = (float*)(ws + alloc((size_t)NNODES * 4 * 4));
  int* row_start = (int*)(ws + alloc((NNODES + 1) * 4));
  int* fill      = (int*)(ws + alloc(NNODES * 4));
  int* csr       = (int*)(ws + alloc(NEDGES * 4));
  int* blocksum  = (int*)(ws + alloc(SCAN_NB * 4));
  int* blockoff  = (int*)(ws + alloc(SCAN_NB * 4));

  // prep (independent of CSR)
  k_cvt_pack<<<(NNODES * 4 + 255) / 256, 256, 0, stream>>>(x, Ahp, Alp, NNODES * 4);
  k_prep_w3<<<(3584 + 255) / 256, 256, 0, stream>>>(lin0, lin1, lin2, wh0, wl0, wh1, wl1, wh2, wl2);

  // Build dst-sorted CSR (self-loops handled implicitly)
  k_zero<<<(NNODES + 255) / 256, 256, 0, stream>>>(fill, NNODES);
  k_hist<<<(NEDGES + 255) / 256, 256, 0, stream>>>(dstA, fill, NEDGES);
  k_scan1<<<SCAN_NB, 256, 0, stream>>>(fill, row_start, blocksum, NNODES);
  k_scan2<<<1, 128, 0, stream>>>(blocksum, blockoff, row_start, SCAN_NB, NNODES);
  k_scan3<<<SCAN_NB, 256, 0, stream>>>(row_start, blockoff, fill, NNODES);
  k_scatter<<<(NEDGES + 255) / 256, 256, 0, stream>>>(srcA, dstA, row_start, fill, csr, NEDGES);

  dim3 g44((NNODES + 63) / 64, 2);   // 4-head GEMMs: BM=64, BN=128
  dim3 g21((NNODES + 63) / 64, 1);   // 1-head GEMM:  BM=64, BN=64

  // ---- layer 0 (IN=128 -> 4x64, concat) ----
  k_gemm_mfma<128, 2, 4><<<g44, 256, 0, stream>>>(Ahp, Alp, wh0, wl0, as0, ad0, h16, vas, vad, NNODES, 256);
  k_gat4<<<5000, 256, 0, stream>>>(h16, vas, vad, row_start, csr, b0, Ahp, Alp);

  // ---- layer 1 (256 -> 4x64, concat) ----
  k_gemm_mfma<256, 2, 4><<<g44, 256, 0, stream>>>(Ahp, Alp, wh1, wl1, as1, ad1, h16, vas, vad, NNODES, 256);
  k_gat4<<<5000, 256, 0, stream>>>(h16, vas, vad, row_start, csr, b1l, Ahp, Alp);

  // ---- layer 2 (256 -> 64, 1 head, mean) + MLP ----
  k_gemm_mfma<256, 1, 1><<<g21, 256, 0, stream>>>(Ahp, Alp, wh2, wl2, as2, ad2, h16, vas, vad, NNODES, 64);
  k_gat1<<<5000, 256, 0, stream>>>(h16, vas, vad, row_start, csr, b2l, w1, mb1, w2, mb2, outp);
}

// Round 11
// 190.096 us; speedup vs baseline: 1.3797x; 1.0201x over previous
//
#include <hip/hip_runtime.h>

#define NNODES 20000
#define NEDGES 320000
#define SCAN_NB ((NNODES + 255) / 256)   // 79
#define DCAP 120                          // per-node cached-logit cap (mean deg 16)

typedef __attribute__((ext_vector_type(8))) short bf16x8;
typedef __attribute__((ext_vector_type(4))) float f32x4;
typedef _Float16 f16x4 __attribute__((ext_vector_type(4)));
typedef _Float16 f16x8 __attribute__((ext_vector_type(8)));

__device__ __forceinline__ float leaky(float x) { return x > 0.f ? x : 0.2f * x; }
__device__ __forceinline__ float elu(float x) { return x > 0.f ? x : expm1f(x); }

__device__ __forceinline__ ushort f2bf(float f) {
  uint u = __float_as_uint(f);
  uint r = (u + 0x7fffu + ((u >> 16) & 1u)) >> 16;
  return (ushort)r;
}
__device__ __forceinline__ float bf2f(ushort h) {
  return __uint_as_float(((uint)h) << 16);
}

// async 16B global->LDS (DMA; zero VGPR cost; compiler cannot serialize it)
__device__ __forceinline__ void gll16(const ushort* g, ushort* l) {
  __builtin_amdgcn_global_load_lds((const __attribute__((address_space(1))) void*)g,
                                   (__attribute__((address_space(3))) void*)l, 16, 0, 0);
}

// ---------------- CSR build ----------------
__global__ void k_hist(const int* __restrict__ dst, int* __restrict__ cnt, int e) {
  int i = blockIdx.x * blockDim.x + threadIdx.x;
  if (i < e) atomicAdd(&cnt[dst[i]], 1);
}

__global__ __launch_bounds__(256) void k_scan1(const int* __restrict__ cnt, int* __restrict__ row_start,
                                               int* __restrict__ blocksum, int n) {
  __shared__ int s[256];
  int t = threadIdx.x;
  int i = blockIdx.x * 256 + t;
  int v = (i < n) ? cnt[i] : 0;
  s[t] = v;
  __syncthreads();
  for (int off = 1; off < 256; off <<= 1) {
    int x = (t >= off) ? s[t - off] : 0;
    __syncthreads();
    s[t] += x;
    __syncthreads();
  }
  if (i < n) row_start[i] = s[t] - v;
  if (t == 255) blocksum[blockIdx.x] = s[255];
}

__global__ __launch_bounds__(128) void k_scan2(int* __restrict__ blocksum, int* __restrict__ blockoff,
                                               int* __restrict__ row_start, int nb, int n) {
  __shared__ int s[128];
  int t = threadIdx.x;
  int v = (t < nb) ? blocksum[t] : 0;
  s[t] = v;
  __syncthreads();
  for (int off = 1; off < 128; off <<= 1) {
    int x = (t >= off) ? s[t - off] : 0;
    __syncthreads();
    s[t] += x;
    __syncthreads();
  }
  if (t < nb) blockoff[t] = s[t] - v;
  if (t == nb - 1) row_start[n] = s[t];
}

__global__ __launch_bounds__(256) void k_scan3(int* __restrict__ row_start, const int* __restrict__ blockoff,
                                               int* __restrict__ fill, int n) {
  int i = blockIdx.x * 256 + threadIdx.x;
  if (i < n) {
    row_start[i] += blockoff[blockIdx.x];
    fill[i] = 0;
  }
}

__global__ void k_scatter(const int* __restrict__ src, const int* __restrict__ dst,
                          const int* __restrict__ row_start, int* __restrict__ fill,
                          int* __restrict__ csr, int e) {
  int i = blockIdx.x * blockDim.x + threadIdx.x;
  if (i < e) {
    int d = dst[i];
    int p = row_start[d] + atomicAdd(&fill[d], 1);
    csr[p] = src[i];
  }
}

// ---------------- fp32 -> packed hi/lo bf16 (MFMA fragment order); also zeroes fill ----------------
__global__ void k_cvt_pack(const float* __restrict__ a, ushort* __restrict__ hi,
                           ushort* __restrict__ lo, int total, int* __restrict__ fill) {
  int i = blockIdx.x * blockDim.x + threadIdx.x;
  if (i < NNODES) fill[i] = 0;
  if (i >= total) return;
  const float* src = a + (size_t)i * 32;
  ushort h[32], lw[32];
#pragma unroll
  for (int r = 0; r < 32; r++) {
    int p = (r < 16) ? ((r >> 2) * 8 + (r & 3)) : (((r - 16) >> 2) * 8 + 4 + (r & 3));
    float v = src[r];
    ushort hh = f2bf(v);
    h[p] = hh;
    lw[p] = f2bf(v - bf2f(hh));
  }
  ushort* ho = hi + (size_t)i * 32;
  ushort* llo = lo + (size_t)i * 32;
#pragma unroll
  for (int q = 0; q < 4; q++) {
    *(bf16x8*)&ho[q * 8] = *(bf16x8*)&h[q * 8];
    *(bf16x8*)&llo[q * 8] = *(bf16x8*)&lw[q * 8];
  }
}

// all three weight matrices in one dispatch
__device__ __forceinline__ void prep_w_one(const float* __restrict__ w, ushort* __restrict__ th,
                                           ushort* __restrict__ tl, int K, int OC, int idx) {
  int KC = K / 32;
  int oc = idx / KC, c = idx % KC;
  ushort h[32], lw[32];
#pragma unroll
  for (int r = 0; r < 32; r++) {
    int p = (r < 16) ? ((r >> 2) * 8 + (r & 3)) : (((r - 16) >> 2) * 8 + 4 + (r & 3));
    float v = w[(size_t)(c * 32 + r) * OC + oc];
    ushort hh = f2bf(v);
    h[p] = hh;
    lw[p] = f2bf(v - bf2f(hh));
  }
  ushort* ho = th + (size_t)oc * K + c * 32;
  ushort* llo = tl + (size_t)oc * K + c * 32;
#pragma unroll
  for (int q = 0; q < 4; q++) {
    *(bf16x8*)&ho[q * 8] = *(bf16x8*)&h[q * 8];
    *(bf16x8*)&llo[q * 8] = *(bf16x8*)&lw[q * 8];
  }
}

__global__ void k_prep_w3(const float* __restrict__ w0, const float* __restrict__ w1,
                          const float* __restrict__ w2,
                          ushort* __restrict__ th0, ushort* __restrict__ tl0,
                          ushort* __restrict__ th1, ushort* __restrict__ tl1,
                          ushort* __restrict__ th2, ushort* __restrict__ tl2) {
  int i = blockIdx.x * blockDim.x + threadIdx.x;
  if (i < 1024) prep_w_one(w0, th0, tl0, 128, 256, i);
  else if (i < 3072) prep_w_one(w1, th1, tl1, 256, 256, i - 1024);
  else if (i < 3584) prep_w_one(w2, th2, tl2, 256, 64, i - 3072);
}

// ---------------- MFMA GEMM: async LDS double-buffer, fused asd epilogue ----------------
template <int K, int NCT, int HEADS>
__global__ __launch_bounds__(256) void k_gemm_mfma(const ushort* __restrict__ Ah, const ushort* __restrict__ Al,
                                                   const ushort* __restrict__ Bh, const ushort* __restrict__ Bl,
                                                   const float* __restrict__ asrc, const float* __restrict__ adst,
                                                   _Float16* __restrict__ H, float* __restrict__ a_s,
                                                   float* __restrict__ a_d, int M, int OC) {
  constexpr int BM = 64, BN = NCT * 64, NC = K / 32;
  constexpr int ALO = 2048;
  constexpr int BOFF = 4096;
  constexpr int BLO = BOFF + BN * 32;
  constexpr int BUFE = BOFF + BN * 64;
  __shared__ ushort sb0[BUFE], sb1[BUFE];
  __shared__ float sh_s[4][64], sh_d[4][64];
  int w = threadIdx.x >> 6, l = threadIdx.x & 63;
  int n0 = blockIdx.x * BM;
  int cw = blockIdx.y * BN + w * (NCT * 16);
  int lr = l & 15;

  int q = l & 3;
  int srow = 16 * w + (l >> 2);
  int sgrow = min(n0 + srow, M - 1);
  int gA = q ^ ((srow >> 1) & 3);
  const ushort* aH = Ah + (size_t)sgrow * K + gA * 8;
  const ushort* aL = Al + (size_t)sgrow * K + gA * 8;
  const ushort* bH[NCT];
  const ushort* bL[NCT];
  int colb[NCT];
#pragma unroll
  for (int i = 0; i < NCT; i++) {
    colb[i] = 16 * NCT * w + 16 * i;
    int sc = colb[i] + (l >> 2);
    int gB = q ^ ((sc >> 1) & 3);
    bH[i] = Bh + (size_t)(blockIdx.y * BN + sc) * K + gB * 8;
    bL[i] = Bl + (size_t)(blockIdx.y * BN + sc) * K + gB * 8;
  }

#define STAGE(buf, c)                                              \
  {                                                                \
    gll16(aH + (c) * 32, &buf[0 + w * 512]);                       \
    gll16(aL + (c) * 32, &buf[ALO + w * 512]);                     \
    _Pragma("unroll") for (int i = 0; i < NCT; i++) {              \
      gll16(bH[i] + (c) * 32, &buf[BOFF + colb[i] * 32]);          \
      gll16(bL[i] + (c) * 32, &buf[BLO + colb[i] * 32]);           \
    }                                                              \
  }

  f32x4 acc[4][NCT];
#pragma unroll
  for (int r = 0; r < 4; r++)
#pragma unroll
    for (int t = 0; t < NCT; t++) acc[r][t] = (f32x4){0.f, 0.f, 0.f, 0.f};

#define COMP(buf)                                                                   \
  {                                                                                 \
    bf16x8 bhf[NCT], blf[NCT];                                                      \
    _Pragma("unroll") for (int t = 0; t < NCT; t++) {                               \
      int bcol = 16 * NCT * w + 16 * t + lr;                                        \
      int gb = (l >> 4) ^ ((bcol >> 1) & 3);                                        \
      bhf[t] = *(const bf16x8*)&buf[BOFF + bcol * 32 + gb * 8];                     \
      blf[t] = *(const bf16x8*)&buf[BLO + bcol * 32 + gb * 8];                      \
    }                                                                               \
    _Pragma("unroll") for (int r = 0; r < 4; r++) {                                 \
      int arow = 16 * r + lr;                                                       \
      int ga = (l >> 4) ^ ((arow >> 1) & 3);                                        \
      bf16x8 ahf = *(const bf16x8*)&buf[arow * 32 + ga * 8];                        \
      bf16x8 alf = *(const bf16x8*)&buf[ALO + arow * 32 + ga * 8];                  \
      _Pragma("unroll") for (int t = 0; t < NCT; t++) {                             \
        acc[r][t] = __builtin_amdgcn_mfma_f32_16x16x32_bf16(ahf, bhf[t], acc[r][t], 0, 0, 0); \
        acc[r][t] = __builtin_amdgcn_mfma_f32_16x16x32_bf16(alf, bhf[t], acc[r][t], 0, 0, 0); \
        acc[r][t] = __builtin_amdgcn_mfma_f32_16x16x32_bf16(ahf, blf[t], acc[r][t], 0, 0, 0); \
      }                                                                             \
    }                                                                               \
  }

  ushort* cur = sb0;
  ushort* nxt = sb1;
  STAGE(cur, 0);
  __syncthreads();
  for (int c = 0; c < NC; ++c) {
    if (c + 1 < NC) STAGE(nxt, c + 1);
    COMP(cur);
    __syncthreads();
    ushort* tmp = cur; cur = nxt; nxt = tmp;
  }
#undef STAGE
#undef COMP

#pragma unroll
  for (int r = 0; r < 4; r++)
#pragma unroll
    for (int t = 0; t < NCT; t++)
#pragma unroll
      for (int reg = 0; reg < 4; reg++) {
        int row = n0 + 16 * r + (l >> 4) * 4 + reg;
        if (row < M) H[(size_t)row * OC + cw + 16 * t + lr] = (_Float16)acc[r][t][reg];
      }

  float asv[NCT], adv[NCT];
#pragma unroll
  for (int t = 0; t < NCT; t++) {
    asv[t] = asrc[cw + 16 * t + lr];
    adv[t] = adst[cw + 16 * t + lr];
  }
#pragma unroll
  for (int r = 0; r < 4; r++) {
#pragma unroll
    for (int reg = 0; reg < 4; reg++) {
      float ps = 0.f, pd = 0.f;
#pragma unroll
      for (int t = 0; t < NCT; t++) {
        ps += acc[r][t][reg] * asv[t];
        pd += acc[r][t][reg] * adv[t];
      }
#pragma unroll
      for (int mask = 1; mask < 16; mask <<= 1) {
        ps += __shfl_xor(ps, mask, 64);
        pd += __shfl_xor(pd, mask, 64);
      }
      int rl = 16 * r + (l >> 4) * 4 + reg;
      if (lr == 0) { sh_s[w][rl] = ps; sh_d[w][rl] = pd; }
    }
  }
  __syncthreads();
  int tid = threadIdx.x;
  if (HEADS == 4) {
    if (tid < 128) {
      int rr = tid & 63, hl = tid >> 6;
      int row = n0 + rr;
      if (row < M) {
        int hidx = row * 4 + blockIdx.y * 2 + hl;
        a_s[hidx] = sh_s[2 * hl][rr] + sh_s[2 * hl + 1][rr];
        a_d[hidx] = sh_d[2 * hl][rr] + sh_d[2 * hl + 1][rr];
      }
    }
  } else {
    if (tid < 64) {
      int row = n0 + tid;
      if (row < M) {
        a_s[row] = sh_s[0][tid] + sh_s[1][tid] + sh_s[2][tid] + sh_s[3][tid];
        a_d[row] = sh_d[0][tid] + sh_d[1][tid] + sh_d[2][tid] + sh_d[3][tid];
      }
    }
  }
}

// ---------------- fused softmax + gather (4 heads): LDS logit cache, 2 edges/wave-pass ----------------
// Phase 1: lanes (head=l>>4, sub=l&15) compute per-head online (m,s), cache logits in LDS.
// Phase 2: lane = (half=l>>5, sl=l&31); channels sl*8..+7 (f16x8, 16B); halves take edges j, j+1.
__global__ __launch_bounds__(256) void k_gat4(const _Float16* __restrict__ h, const float* __restrict__ a_s,
                                              const float* __restrict__ a_d, const int* __restrict__ row_start,
                                              const int* __restrict__ csr, const float* __restrict__ bias,
                                              ushort* __restrict__ Ah, ushort* __restrict__ Al) {
  __shared__ float elds[4][DCAP * 4];
  int wid = threadIdx.x >> 6, l = threadIdx.x & 63;
  int n = blockIdx.x * 4 + wid;
  if (n >= NNODES) return;
  int head = l >> 4, sub = l & 15;
  int half = l >> 5, sl = l & 31;
  int head2 = sl >> 3;
  int jb = row_start[n], je = row_start[n + 1];
  float ad = a_d[n * 4 + head];
  float es = leaky(a_s[n * 4 + head] + ad);
  float m = -1e30f, s = 0.f;
  if (sub == 0) { m = es; s = 1.f; }
  for (int j = jb + sub; j < je; j += 16) {
    float e = leaky(a_s[csr[j] * 4 + head] + ad);
    int o = j - jb;
    if (o < DCAP) elds[wid][o * 4 + head] = e;
    float nm = fmaxf(m, e);
    s = s * __expf(m - nm) + __expf(e - nm);
    m = nm;
  }
#pragma unroll
  for (int mask = 1; mask < 16; mask <<= 1) {
    float m2 = __shfl_xor(m, mask, 64);
    float s2 = __shfl_xor(s, mask, 64);
    float nm = fmaxf(m, m2);
    s = s * __expf(m - nm) + s2 * __expf(m2 - nm);
    m = nm;
  }
  __asm__ volatile("" ::: "memory");   // LDS writes ordered before reads (same wave)
  float inv = 1.f / s;
  float sa = __expf(es - m) * inv;
  // redistribute per-head stats to phase-2 layout (lane's channels belong to head2)
  int srcl = head2 << 4;
  float m2r = __shfl(m, srcl, 64);
  float inv2 = __shfl(inv, srcl, 64);
  float sa2 = __shfl(sa, srcl, 64);
  float ad2 = __shfl(ad, srcl, 64);

  float acc[8];
  f16x8 hv = *(const f16x8*)&h[(size_t)n * 256 + sl * 8];
#pragma unroll
  for (int i = 0; i < 8; i++) acc[i] = (half == 0) ? sa2 * (float)hv[i] : 0.f;

  int jcap = min(je, jb + DCAP);
  int j = jb;
  for (; j + 7 < jcap; j += 8) {   // 4 pairs -> 8 edges in flight
    int e0 = j + half, e1 = j + 2 + half, e2 = j + 4 + half, e3 = j + 6 + half;
    int s0 = csr[e0], s1 = csr[e1], s2 = csr[e2], s3 = csr[e3];
    float a0 = __expf(elds[wid][(e0 - jb) * 4 + head2] - m2r) * inv2;
    float a1 = __expf(elds[wid][(e1 - jb) * 4 + head2] - m2r) * inv2;
    float a2 = __expf(elds[wid][(e2 - jb) * 4 + head2] - m2r) * inv2;
    float a3 = __expf(elds[wid][(e3 - jb) * 4 + head2] - m2r) * inv2;
    f16x8 v0 = *(const f16x8*)&h[(size_t)s0 * 256 + sl * 8];
    f16x8 v1 = *(const f16x8*)&h[(size_t)s1 * 256 + sl * 8];
    f16x8 v2 = *(const f16x8*)&h[(size_t)s2 * 256 + sl * 8];
    f16x8 v3 = *(const f16x8*)&h[(size_t)s3 * 256 + sl * 8];
#pragma unroll
    for (int i = 0; i < 8; i++)
      acc[i] += a0 * (float)v0[i] + a1 * (float)v1[i] + a2 * (float)v2[i] + a3 * (float)v3[i];
  }
  for (; j + 1 < jcap; j += 2) {
    int e0 = j + half;
    int s0 = csr[e0];
    float a0 = __expf(elds[wid][(e0 - jb) * 4 + head2] - m2r) * inv2;
    f16x8 v0 = *(const f16x8*)&h[(size_t)s0 * 256 + sl * 8];
#pragma unroll
    for (int i = 0; i < 8; i++) acc[i] += a0 * (float)v0[i];
  }
  if (j < jcap) {   // unpaired edge within cap: half 0 only
    int s0 = csr[j];
    float a0 = (half == 0) ? __expf(elds[wid][(j - jb) * 4 + head2] - m2r) * inv2 : 0.f;
    f16x8 v0 = *(const f16x8*)&h[(size_t)s0 * 256 + sl * 8];
#pragma unroll
    for (int i = 0; i < 8; i++) acc[i] += a0 * (float)v0[i];
    j++;
  }
  for (; j < je; j++) {   // overflow fallback (deg > DCAP), half 0 only
    int s0 = csr[j];
    float a0 = (half == 0) ? __expf(leaky(a_s[s0 * 4 + head2] + ad2) - m2r) * inv2 : 0.f;
    f16x8 v0 = *(const f16x8*)&h[(size_t)s0 * 256 + sl * 8];
#pragma unroll
    for (int i = 0; i < 8; i++) acc[i] += a0 * (float)v0[i];
  }
  // combine halves (both cover the same channels)
#pragma unroll
  for (int i = 0; i < 8; i++) acc[i] += __shfl_xor(acc[i], 32, 64);

  // epilogue: lane stores channels c0 = sl*8 + half*4 (its acc[half*4..+3])
  int c0 = sl * 8 + half * 4;
  int k = c0 & 31;
  size_t base = (size_t)n * 256 + (c0 >> 5) * 32 + ((k < 16) ? (k >> 2) * 8 : (((k - 16) >> 2) * 8 + 4));
  float4 b = *(const float4*)&bias[c0];
  int ai = half * 4;
  float o0 = elu(acc[ai + 0] + b.x);
  float o1 = elu(acc[ai + 1] + b.y);
  float o2 = elu(acc[ai + 2] + b.z);
  float o3 = elu(acc[ai + 3] + b.w);
  ushort4 hh, ll;
  hh.x = f2bf(o0); ll.x = f2bf(o0 - bf2f(hh.x));
  hh.y = f2bf(o1); ll.y = f2bf(o1 - bf2f(hh.y));
  hh.z = f2bf(o2); ll.z = f2bf(o2 - bf2f(hh.z));
  hh.w = f2bf(o3); ll.w = f2bf(o3 - bf2f(hh.w));
  *(ushort4*)&Ah[base] = hh;
  *(ushort4*)&Al[base] = ll;
}

// ---------------- fused softmax + gather + MLP (1 head): 4 edge-groups of 16 lanes ----------------
__global__ __launch_bounds__(256) void k_gat1(const _Float16* __restrict__ h, const float* __restrict__ a_s,
                                              const float* __restrict__ a_d, const int* __restrict__ row_start,
                                              const int* __restrict__ csr, const float* __restrict__ bias,
                                              const float* __restrict__ w1, const float* __restrict__ b1,
                                              const float* __restrict__ w2, const float* __restrict__ b2,
                                              float* __restrict__ out) {
  __shared__ float elds[4][DCAP];
  __shared__ float sh[4][64];
  int wid = threadIdx.x >> 6, l = threadIdx.x & 63;
  int n = blockIdx.x * 4 + wid;
  int grp = l >> 4, cl = l & 15;
  float acc[4] = {0.f, 0.f, 0.f, 0.f};
  if (n < NNODES) {
    int jb = row_start[n], je = row_start[n + 1];
    float ad = a_d[n];
    float es = leaky(a_s[n] + ad);
    float m = -1e30f, s = 0.f;
    if (l == 0) { m = es; s = 1.f; }
    for (int j = jb + l; j < je; j += 64) {
      float e = leaky(a_s[csr[j]] + ad);
      int o = j - jb;
      if (o < DCAP) elds[wid][o] = e;
      float nm = fmaxf(m, e);
      s = s * __expf(m - nm) + __expf(e - nm);
      m = nm;
    }
#pragma unroll
    for (int mask = 1; mask < 64; mask <<= 1) {
      float m2 = __shfl_xor(m, mask, 64);
      float s2 = __shfl_xor(s, mask, 64);
      float nm = fmaxf(m, m2);
      s = s * __expf(m - nm) + s2 * __expf(m2 - nm);
      m = nm;
    }
    __asm__ volatile("" ::: "memory");
    float inv = 1.f / s;
    float sa = __expf(es - m) * inv;
    f16x4 hv = *(const f16x4*)&h[(size_t)n * 64 + cl * 4];
    if (grp == 0) {
#pragma unroll
      for (int i = 0; i < 4; i++) acc[i] = sa * (float)hv[i];
    }
    int jcap = min(je, jb + DCAP);
    int j = jb;
    for (; j + 7 < jcap; j += 8) {   // 2 group-passes -> 8 edges in flight
      int e0 = j + grp, e1 = j + 4 + grp;
      int s0 = csr[e0], s1 = csr[e1];
      float a0 = __expf(elds[wid][e0 - jb] - m) * inv;
      float a1 = __expf(elds[wid][e1 - jb] - m) * inv;
      f16x4 v0 = *(const f16x4*)&h[(size_t)s0 * 64 + cl * 4];
      f16x4 v1 = *(const f16x4*)&h[(size_t)s1 * 64 + cl * 4];
#pragma unroll
      for (int i = 0; i < 4; i++) acc[i] += a0 * (float)v0[i] + a1 * (float)v1[i];
    }
    for (; j + 3 < jcap; j += 4) {
      int e0 = j + grp;
      int s0 = csr[e0];
      float a0 = __expf(elds[wid][e0 - jb] - m) * inv;
      f16x4 v0 = *(const f16x4*)&h[(size_t)s0 * 64 + cl * 4];
#pragma unroll
      for (int i = 0; i < 4; i++) acc[i] += a0 * (float)v0[i];
    }
    if (j + grp < jcap) {   // tail: groups 0..r-1 take one edge each
      int e0 = j + grp;
      int s0 = csr[e0];
      float a0 = __expf(elds[wid][e0 - jb] - m) * inv;
      f16x4 v0 = *(const f16x4*)&h[(size_t)s0 * 64 + cl * 4];
#pragma unroll
      for (int i = 0; i < 4; i++) acc[i] += a0 * (float)v0[i];
    }
    for (int jj = jcap; jj < je; jj += 4) {   // overflow fallback
      int e0 = jj + grp;
      if (e0 < je) {
        int s0 = csr[e0];
        float a0 = __expf(leaky(a_s[s0] + ad) - m) * inv;
        f16x4 v0 = *(const f16x4*)&h[(size_t)s0 * 64 + cl * 4];
#pragma unroll
        for (int i = 0; i < 4; i++) acc[i] += a0 * (float)v0[i];
      }
    }
  }
  // combine the 4 edge-groups
#pragma unroll
  for (int i = 0; i < 4; i++) {
    acc[i] += __shfl_xor(acc[i], 16, 64);
    acc[i] += __shfl_xor(acc[i], 32, 64);
  }
  if (n < NNODES && l < 16) {
#pragma unroll
    for (int i = 0; i < 4; i++) sh[wid][cl * 4 + i] = elu(acc[i] + bias[cl * 4 + i]);
  }
  __syncthreads();
  float r = 0.f;
  if (l < 32 && n < NNODES) {
    r = b1[l];
#pragma unroll 8
    for (int k = 0; k < 64; k++) r += sh[wid][k] * w1[k * 32 + l];
    r = fmaxf(r, 0.f);
    r *= w2[l];
  }
  for (int mask = 16; mask >= 1; mask >>= 1) r += __shfl_xor(r, mask, 64);
  if (l == 0 && n < NNODES) out[n] = r + b2[0];
}

extern "C" void kernel_launch(void* const* d_in, const int* in_sizes, int n_in,
                              void* d_out, int out_size, void* d_ws, size_t ws_size,
                              hipStream_t stream) {
  const float* x    = (const float*)d_in[0];
  const int*   eidx = (const int*)d_in[1];
  const float* lin0 = (const float*)d_in[2];
  const float* as0  = (const float*)d_in[3];
  const float* ad0  = (const float*)d_in[4];
  const float* b0   = (const float*)d_in[5];
  const float* lin1 = (const float*)d_in[6];
  const float* as1  = (const float*)d_in[7];
  const float* ad1  = (const float*)d_in[8];
  const float* b1l  = (const float*)d_in[9];
  const float* lin2 = (const float*)d_in[10];
  const float* as2  = (const float*)d_in[11];
  const float* ad2  = (const float*)d_in[12];
  const float* b2l  = (const float*)d_in[13];
  const float* w1   = (const float*)d_in[14];
  const float* mb1  = (const float*)d_in[15];
  const float* w2   = (const float*)d_in[16];
  const float* mb2  = (const float*)d_in[17];
  float* outp = (float*)d_out;

  const int* srcA = eidx;
  const int* dstA = eidx + NEDGES;

  char* ws = (char*)d_ws;
  size_t o = 0;
  auto alloc = [&](size_t bytes) { size_t r = o; o += (bytes + 255) & ~255UL; return r; };
  _Float16* h16 = (_Float16*)(ws + alloc((size_t)NNODES * 256 * 2));
  ushort* Ahp = (ushort*)(ws + alloc((size_t)NNODES * 256 * 2));
  ushort* Alp = (ushort*)(ws + alloc((size_t)NNODES * 256 * 2));
  ushort* wh0 = (ushort*)(ws + alloc(128 * 256 * 2));
  ushort* wl0 = (ushort*)(ws + alloc(128 * 256 * 2));
  ushort* wh1 = (ushort*)(ws + alloc(256 * 256 * 2));
  ushort* wl1 = (ushort*)(ws + alloc(256 * 256 * 2));
  ushort* wh2 = (ushort*)(ws + alloc(256 * 64 * 2));
  ushort* wl2 = (ushort*)(ws + alloc(256 * 64 * 2));
  float*  vas = (float*)(ws + alloc((size_t)NNODES * 4 * 4));
  float*  vad = (float*)(ws + alloc((size_t)NNODES * 4 * 4));
  int* row_start = (int*)(ws + alloc((NNODES + 1) * 4));
  int* fill      = (int*)(ws + alloc(NNODES * 4));
  int* csr       = (int*)(ws + alloc(NEDGES * 4));
  int* blocksum  = (int*)(ws + alloc(SCAN_NB * 4));
  int* blockoff  = (int*)(ws + alloc(SCAN_NB * 4));

  // prep (also zeroes fill for the histogram)
  k_cvt_pack<<<(NNODES * 4 + 255) / 256, 256, 0, stream>>>(x, Ahp, Alp, NNODES * 4, fill);
  k_prep_w3<<<(3584 + 255) / 256, 256, 0, stream>>>(lin0, lin1, lin2, wh0, wl0, wh1, wl1, wh2, wl2);

  // Build dst-sorted CSR (self-loops handled implicitly)
  k_hist<<<(NEDGES + 255) / 256, 256, 0, stream>>>(dstA, fill, NEDGES);
  k_scan1<<<SCAN_NB, 256, 0, stream>>>(fill, row_start, blocksum, NNODES);
  k_scan2<<<1, 128, 0, stream>>>(blocksum, blockoff, row_start, SCAN_NB, NNODES);
  k_scan3<<<SCAN_NB, 256, 0, stream>>>(row_start, blockoff, fill, NNODES);
  k_scatter<<<(NEDGES + 255) / 256, 256, 0, stream>>>(srcA, dstA, row_start, fill, csr, NEDGES);

  dim3 g44((NNODES + 63) / 64, 2);   // 4-head GEMMs: BM=64, BN=128
  dim3 g21((NNODES + 63) / 64, 1);   // 1-head GEMM:  BM=64, BN=64

  // ---- layer 0 (IN=128 -> 4x64, concat) ----
  k_gemm_mfma<128, 2, 4><<<g44, 256, 0, stream>>>(Ahp, Alp, wh0, wl0, as0, ad0, h16, vas, vad, NNODES, 256);
  k_gat4<<<5000, 256, 0, stream>>>(h16, vas, vad, row_start, csr, b0, Ahp, Alp);

  // ---- layer 1 (256 -> 4x64, concat) ----
  k_gemm_mfma<256, 2, 4><<<g44, 256, 0, stream>>>(Ahp, Alp, wh1, wl1, as1, ad1, h16, vas, vad, NNODES, 256);
  k_gat4<<<5000, 256, 0, stream>>>(h16, vas, vad, row_start, csr, b1l, Ahp, Alp);

  // ---- layer 2 (256 -> 64, 1 head, mean) + MLP ----
  k_gemm_mfma<256, 1, 1><<<g21, 256, 0, stream>>>(Ahp, Alp, wh2, wl2, as2, ad2, h16, vas, vad, NNODES, 64);
  k_gat1<<<5000, 256, 0, stream>>>(h16, vas, vad, row_start, csr, b2l, w1, mb1, w2, mb2, outp);
}

// Round 12
// 181.887 us; speedup vs baseline: 1.4420x; 1.0451x over previous
//
#include <hip/hip_runtime.h>

#define NNODES 20000
#define NEDGES 320000
#define SCAN_NB ((NNODES + 255) / 256)   // 79
#define DCAP 120                          // per-node cached-logit cap (mean deg 16)

typedef __attribute__((ext_vector_type(8))) short bf16x8;
typedef __attribute__((ext_vector_type(4))) float f32x4;
typedef _Float16 f16x4 __attribute__((ext_vector_type(4)));
typedef _Float16 f16x8 __attribute__((ext_vector_type(8)));

__device__ __forceinline__ float leaky(float x) { return x > 0.f ? x : 0.2f * x; }
__device__ __forceinline__ float elu(float x) { return x > 0.f ? x : expm1f(x); }

// async 16B global->LDS (DMA; zero VGPR cost; compiler cannot serialize it)
__device__ __forceinline__ void gll16(const ushort* g, ushort* l) {
  __builtin_amdgcn_global_load_lds((const __attribute__((address_space(1))) void*)g,
                                   (__attribute__((address_space(3))) void*)l, 16, 0, 0);
}

// ---------------- CSR build ----------------
__global__ __launch_bounds__(256) void k_scan1(const int* __restrict__ cnt, int* __restrict__ row_start,
                                               int* __restrict__ blocksum, int n) {
  __shared__ int s[256];
  int t = threadIdx.x;
  int i = blockIdx.x * 256 + t;
  int v = (i < n) ? cnt[i] : 0;
  s[t] = v;
  __syncthreads();
  for (int off = 1; off < 256; off <<= 1) {
    int x = (t >= off) ? s[t - off] : 0;
    __syncthreads();
    s[t] += x;
    __syncthreads();
  }
  if (i < n) row_start[i] = s[t] - v;
  if (t == 255) blocksum[blockIdx.x] = s[255];
}

__global__ __launch_bounds__(128) void k_scan2(int* __restrict__ blocksum, int* __restrict__ blockoff,
                                               int* __restrict__ row_start, int nb, int n) {
  __shared__ int s[128];
  int t = threadIdx.x;
  int v = (t < nb) ? blocksum[t] : 0;
  s[t] = v;
  __syncthreads();
  for (int off = 1; off < 128; off <<= 1) {
    int x = (t >= off) ? s[t - off] : 0;
    __syncthreads();
    s[t] += x;
    __syncthreads();
  }
  if (t < nb) blockoff[t] = s[t] - v;
  if (t == nb - 1) row_start[n] = s[t];
}

__global__ __launch_bounds__(256) void k_scan3(int* __restrict__ row_start, const int* __restrict__ blockoff,
                                               int* __restrict__ fill, int n) {
  int i = blockIdx.x * 256 + threadIdx.x;
  if (i < n) {
    row_start[i] += blockoff[blockIdx.x];
    fill[i] = 0;
  }
}

__global__ void k_scatter(const int* __restrict__ src, const int* __restrict__ dst,
                          const int* __restrict__ row_start, int* __restrict__ fill,
                          int* __restrict__ csr, int e) {
  int i = blockIdx.x * blockDim.x + threadIdx.x;
  if (i < e) {
    int d = dst[i];
    int p = row_start[d] + atomicAdd(&fill[d], 1);
    csr[p] = src[i];
  }
}

// ---------------- fp32 -> f16 fragment-packed + dst histogram (fused) ----------------
// pack: thread i < NNODES*4 handles 32-k chunk i; hist: thread i < NEDGES counts dst.
__global__ void k_cvt_hist(const float* __restrict__ a, _Float16* __restrict__ Ap, int total,
                           const int* __restrict__ dst, int* __restrict__ cnt, int e) {
  int i = blockIdx.x * blockDim.x + threadIdx.x;
  if (i < e) atomicAdd(&cnt[dst[i]], 1);
  if (i >= total) return;
  const float* src = a + (size_t)i * 32;
  _Float16 h[32];
#pragma unroll
  for (int r = 0; r < 32; r++) {
    int p = (r < 16) ? ((r >> 2) * 8 + (r & 3)) : (((r - 16) >> 2) * 8 + 4 + (r & 3));
    h[p] = (_Float16)src[r];
  }
  _Float16* ho = Ap + (size_t)i * 32;
#pragma unroll
  for (int q = 0; q < 4; q++) *(f16x8*)&ho[q * 8] = *(f16x8*)&h[q * 8];
}

// all three weight matrices packed to f16 [OC][K] fragment order; also zeroes fill
__device__ __forceinline__ void prep_w_one(const float* __restrict__ w, _Float16* __restrict__ th,
                                           int K, int OC, int idx) {
  int KC = K / 32;
  int oc = idx / KC, c = idx % KC;
  _Float16 h[32];
#pragma unroll
  for (int r = 0; r < 32; r++) {
    int p = (r < 16) ? ((r >> 2) * 8 + (r & 3)) : (((r - 16) >> 2) * 8 + 4 + (r & 3));
    h[p] = (_Float16)w[(size_t)(c * 32 + r) * OC + oc];
  }
  _Float16* ho = th + (size_t)oc * K + c * 32;
#pragma unroll
  for (int q = 0; q < 4; q++) *(f16x8*)&ho[q * 8] = *(f16x8*)&h[q * 8];
}

__global__ void k_prep_w3z(const float* __restrict__ w0, const float* __restrict__ w1,
                           const float* __restrict__ w2,
                           _Float16* __restrict__ th0, _Float16* __restrict__ th1,
                           _Float16* __restrict__ th2, int* __restrict__ fill) {
  int i = blockIdx.x * blockDim.x + threadIdx.x;
  if (i < NNODES) fill[i] = 0;
  if (i < 1024) prep_w_one(w0, th0, 128, 256, i);
  else if (i < 3072) prep_w_one(w1, th1, 256, 256, i - 1024);
  else if (i < 3584) prep_w_one(w2, th2, 256, 64, i - 3072);
}

// ---------------- MFMA GEMM (single f16), async LDS double-buffer, fused asd epilogue ----------------
template <int K, int NCT, int HEADS>
__global__ __launch_bounds__(256) void k_gemm_mfma(const ushort* __restrict__ Ah, const ushort* __restrict__ Bh,
                                                   const float* __restrict__ asrc, const float* __restrict__ adst,
                                                   _Float16* __restrict__ H, float* __restrict__ a_s,
                                                   float* __restrict__ a_d, int M, int OC) {
  constexpr int BM = 64, BN = NCT * 64, NC = K / 32;
  constexpr int BOFF = 2048;
  constexpr int BUFE = BOFF + BN * 32;
  __shared__ ushort sb0[BUFE], sb1[BUFE];
  __shared__ float sh_s[4][64], sh_d[4][64];
  int w = threadIdx.x >> 6, l = threadIdx.x & 63;
  int n0 = blockIdx.x * BM;
  int cw = blockIdx.y * BN + w * (NCT * 16);
  int lr = l & 15;

  int q = l & 3;
  int srow = 16 * w + (l >> 2);
  int sgrow = min(n0 + srow, M - 1);
  int gA = q ^ ((srow >> 1) & 3);
  const ushort* aH = Ah + (size_t)sgrow * K + gA * 8;
  const ushort* bH[NCT];
  int colb[NCT];
#pragma unroll
  for (int i = 0; i < NCT; i++) {
    colb[i] = 16 * NCT * w + 16 * i;
    int sc = colb[i] + (l >> 2);
    int gB = q ^ ((sc >> 1) & 3);
    bH[i] = Bh + (size_t)(blockIdx.y * BN + sc) * K + gB * 8;
  }

#define STAGE(buf, c)                                              \
  {                                                                \
    gll16(aH + (c) * 32, &buf[w * 512]);                           \
    _Pragma("unroll") for (int i = 0; i < NCT; i++)                \
      gll16(bH[i] + (c) * 32, &buf[BOFF + colb[i] * 32]);          \
  }

  f32x4 acc[4][NCT];
#pragma unroll
  for (int r = 0; r < 4; r++)
#pragma unroll
    for (int t = 0; t < NCT; t++) acc[r][t] = (f32x4){0.f, 0.f, 0.f, 0.f};

#define COMP(buf)                                                                   \
  {                                                                                 \
    f16x8 bhf[NCT];                                                                 \
    _Pragma("unroll") for (int t = 0; t < NCT; t++) {                               \
      int bcol = 16 * NCT * w + 16 * t + lr;                                        \
      int gb = (l >> 4) ^ ((bcol >> 1) & 3);                                        \
      bhf[t] = *(const f16x8*)&buf[BOFF + bcol * 32 + gb * 8];                      \
    }                                                                               \
    _Pragma("unroll") for (int r = 0; r < 4; r++) {                                 \
      int arow = 16 * r + lr;                                                       \
      int ga = (l >> 4) ^ ((arow >> 1) & 3);                                        \
      f16x8 ahf = *(const f16x8*)&buf[arow * 32 + ga * 8];                          \
      _Pragma("unroll") for (int t = 0; t < NCT; t++)                               \
        acc[r][t] = __builtin_amdgcn_mfma_f32_16x16x32_f16(ahf, bhf[t], acc[r][t], 0, 0, 0); \
    }                                                                               \
  }

  ushort* cur = sb0;
  ushort* nxt = sb1;
  STAGE(cur, 0);
  __syncthreads();
  for (int c = 0; c < NC; ++c) {
    if (c + 1 < NC) STAGE(nxt, c + 1);
    COMP(cur);
    __syncthreads();
    ushort* tmp = cur; cur = nxt; nxt = tmp;
  }
#undef STAGE
#undef COMP

#pragma unroll
  for (int r = 0; r < 4; r++)
#pragma unroll
    for (int t = 0; t < NCT; t++)
#pragma unroll
      for (int reg = 0; reg < 4; reg++) {
        int row = n0 + 16 * r + (l >> 4) * 4 + reg;
        if (row < M) H[(size_t)row * OC + cw + 16 * t + lr] = (_Float16)acc[r][t][reg];
      }

  float asv[NCT], adv[NCT];
#pragma unroll
  for (int t = 0; t < NCT; t++) {
    asv[t] = asrc[cw + 16 * t + lr];
    adv[t] = adst[cw + 16 * t + lr];
  }
#pragma unroll
  for (int r = 0; r < 4; r++) {
#pragma unroll
    for (int reg = 0; reg < 4; reg++) {
      float ps = 0.f, pd = 0.f;
#pragma unroll
      for (int t = 0; t < NCT; t++) {
        ps += acc[r][t][reg] * asv[t];
        pd += acc[r][t][reg] * adv[t];
      }
#pragma unroll
      for (int mask = 1; mask < 16; mask <<= 1) {
        ps += __shfl_xor(ps, mask, 64);
        pd += __shfl_xor(pd, mask, 64);
      }
      int rl = 16 * r + (l >> 4) * 4 + reg;
      if (lr == 0) { sh_s[w][rl] = ps; sh_d[w][rl] = pd; }
    }
  }
  __syncthreads();
  int tid = threadIdx.x;
  if (HEADS == 4) {
    if (tid < 128) {
      int rr = tid & 63, hl = tid >> 6;
      int row = n0 + rr;
      if (row < M) {
        int hidx = row * 4 + blockIdx.y * 2 + hl;
        a_s[hidx] = sh_s[2 * hl][rr] + sh_s[2 * hl + 1][rr];
        a_d[hidx] = sh_d[2 * hl][rr] + sh_d[2 * hl + 1][rr];
      }
    }
  } else {
    if (tid < 64) {
      int row = n0 + tid;
      if (row < M) {
        a_s[row] = sh_s[0][tid] + sh_s[1][tid] + sh_s[2][tid] + sh_s[3][tid];
        a_d[row] = sh_d[0][tid] + sh_d[1][tid] + sh_d[2][tid] + sh_d[3][tid];
      }
    }
  }
}

// ---------------- fused softmax + gather (4 heads): LDS logit cache, 2 edges/wave-pass ----------------
__global__ __launch_bounds__(256) void k_gat4(const _Float16* __restrict__ h, const float* __restrict__ a_s,
                                              const float* __restrict__ a_d, const int* __restrict__ row_start,
                                              const int* __restrict__ csr, const float* __restrict__ bias,
                                              _Float16* __restrict__ Ap) {
  __shared__ float elds[4][DCAP * 4];
  int wid = threadIdx.x >> 6, l = threadIdx.x & 63;
  int n = blockIdx.x * 4 + wid;
  if (n >= NNODES) return;
  int head = l >> 4, sub = l & 15;
  int half = l >> 5, sl = l & 31;
  int head2 = sl >> 3;
  int jb = row_start[n], je = row_start[n + 1];
  float ad = a_d[n * 4 + head];
  float es = leaky(a_s[n * 4 + head] + ad);
  float m = -1e30f, s = 0.f;
  if (sub == 0) { m = es; s = 1.f; }
  for (int j = jb + sub; j < je; j += 16) {
    float e = leaky(a_s[csr[j] * 4 + head] + ad);
    int o = j - jb;
    if (o < DCAP) elds[wid][o * 4 + head] = e;
    float nm = fmaxf(m, e);
    s = s * __expf(m - nm) + __expf(e - nm);
    m = nm;
  }
#pragma unroll
  for (int mask = 1; mask < 16; mask <<= 1) {
    float m2 = __shfl_xor(m, mask, 64);
    float s2 = __shfl_xor(s, mask, 64);
    float nm = fmaxf(m, m2);
    s = s * __expf(m - nm) + s2 * __expf(m2 - nm);
    m = nm;
  }
  __asm__ volatile("" ::: "memory");
  float inv = 1.f / s;
  float sa = __expf(es - m) * inv;
  int srcl = head2 << 4;
  float m2r = __shfl(m, srcl, 64);
  float inv2 = __shfl(inv, srcl, 64);
  float sa2 = __shfl(sa, srcl, 64);
  float ad2 = __shfl(ad, srcl, 64);

  float acc[8];
  f16x8 hv = *(const f16x8*)&h[(size_t)n * 256 + sl * 8];
#pragma unroll
  for (int i = 0; i < 8; i++) acc[i] = (half == 0) ? sa2 * (float)hv[i] : 0.f;

  int jcap = min(je, jb + DCAP);
  int j = jb;
  for (; j + 7 < jcap; j += 8) {
    int e0 = j + half, e1 = j + 2 + half, e2 = j + 4 + half, e3 = j + 6 + half;
    int s0 = csr[e0], s1 = csr[e1], s2 = csr[e2], s3 = csr[e3];
    float a0 = __expf(elds[wid][(e0 - jb) * 4 + head2] - m2r) * inv2;
    float a1 = __expf(elds[wid][(e1 - jb) * 4 + head2] - m2r) * inv2;
    float a2 = __expf(elds[wid][(e2 - jb) * 4 + head2] - m2r) * inv2;
    float a3 = __expf(elds[wid][(e3 - jb) * 4 + head2] - m2r) * inv2;
    f16x8 v0 = *(const f16x8*)&h[(size_t)s0 * 256 + sl * 8];
    f16x8 v1 = *(const f16x8*)&h[(size_t)s1 * 256 + sl * 8];
    f16x8 v2 = *(const f16x8*)&h[(size_t)s2 * 256 + sl * 8];
    f16x8 v3 = *(const f16x8*)&h[(size_t)s3 * 256 + sl * 8];
#pragma unroll
    for (int i = 0; i < 8; i++)
      acc[i] += a0 * (float)v0[i] + a1 * (float)v1[i] + a2 * (float)v2[i] + a3 * (float)v3[i];
  }
  for (; j + 1 < jcap; j += 2) {
    int e0 = j + half;
    int s0 = csr[e0];
    float a0 = __expf(elds[wid][(e0 - jb) * 4 + head2] - m2r) * inv2;
    f16x8 v0 = *(const f16x8*)&h[(size_t)s0 * 256 + sl * 8];
#pragma unroll
    for (int i = 0; i < 8; i++) acc[i] += a0 * (float)v0[i];
  }
  if (j < jcap) {
    int s0 = csr[j];
    float a0 = (half == 0) ? __expf(elds[wid][(j - jb) * 4 + head2] - m2r) * inv2 : 0.f;
    f16x8 v0 = *(const f16x8*)&h[(size_t)s0 * 256 + sl * 8];
#pragma unroll
    for (int i = 0; i < 8; i++) acc[i] += a0 * (float)v0[i];
    j++;
  }
  for (; j < je; j++) {
    int s0 = csr[j];
    float a0 = (half == 0) ? __expf(leaky(a_s[s0 * 4 + head2] + ad2) - m2r) * inv2 : 0.f;
    f16x8 v0 = *(const f16x8*)&h[(size_t)s0 * 256 + sl * 8];
#pragma unroll
    for (int i = 0; i < 8; i++) acc[i] += a0 * (float)v0[i];
  }
#pragma unroll
  for (int i = 0; i < 8; i++) acc[i] += __shfl_xor(acc[i], 32, 64);

  // epilogue: lane stores channels c0 = sl*8 + half*4 as packed f16 for next GEMM
  int c0 = sl * 8 + half * 4;
  int k = c0 & 31;
  size_t base = (size_t)n * 256 + (c0 >> 5) * 32 + ((k < 16) ? (k >> 2) * 8 : (((k - 16) >> 2) * 8 + 4));
  float4 b = *(const float4*)&bias[c0];
  int ai = half * 4;
  f16x4 pk;
  pk[0] = (_Float16)elu(acc[ai + 0] + b.x);
  pk[1] = (_Float16)elu(acc[ai + 1] + b.y);
  pk[2] = (_Float16)elu(acc[ai + 2] + b.z);
  pk[3] = (_Float16)elu(acc[ai + 3] + b.w);
  *(f16x4*)&Ap[base] = pk;
}

// ---------------- fused softmax + gather + MLP (1 head): 4 edge-groups of 16 lanes ----------------
__global__ __launch_bounds__(256) void k_gat1(const _Float16* __restrict__ h, const float* __restrict__ a_s,
                                              const float* __restrict__ a_d, const int* __restrict__ row_start,
                                              const int* __restrict__ csr, const float* __restrict__ bias,
                                              const float* __restrict__ w1, const float* __restrict__ b1,
                                              const float* __restrict__ w2, const float* __restrict__ b2,
                                              float* __restrict__ out) {
  __shared__ float elds[4][DCAP];
  __shared__ float sh[4][64];
  int wid = threadIdx.x >> 6, l = threadIdx.x & 63;
  int n = blockIdx.x * 4 + wid;
  int grp = l >> 4, cl = l & 15;
  float acc[4] = {0.f, 0.f, 0.f, 0.f};
  if (n < NNODES) {
    int jb = row_start[n], je = row_start[n + 1];
    float ad = a_d[n];
    float es = leaky(a_s[n] + ad);
    float m = -1e30f, s = 0.f;
    if (l == 0) { m = es; s = 1.f; }
    for (int j = jb + l; j < je; j += 64) {
      float e = leaky(a_s[csr[j]] + ad);
      int o = j - jb;
      if (o < DCAP) elds[wid][o] = e;
      float nm = fmaxf(m, e);
      s = s * __expf(m - nm) + __expf(e - nm);
      m = nm;
    }
#pragma unroll
    for (int mask = 1; mask < 64; mask <<= 1) {
      float m2 = __shfl_xor(m, mask, 64);
      float s2 = __shfl_xor(s, mask, 64);
      float nm = fmaxf(m, m2);
      s = s * __expf(m - nm) + s2 * __expf(m2 - nm);
      m = nm;
    }
    __asm__ volatile("" ::: "memory");
    float inv = 1.f / s;
    float sa = __expf(es - m) * inv;
    f16x4 hv = *(const f16x4*)&h[(size_t)n * 64 + cl * 4];
    if (grp == 0) {
#pragma unroll
      for (int i = 0; i < 4; i++) acc[i] = sa * (float)hv[i];
    }
    int jcap = min(je, jb + DCAP);
    int j = jb;
    for (; j + 7 < jcap; j += 8) {
      int e0 = j + grp, e1 = j + 4 + grp;
      int s0 = csr[e0], s1 = csr[e1];
      float a0 = __expf(elds[wid][e0 - jb] - m) * inv;
      float a1 = __expf(elds[wid][e1 - jb] - m) * inv;
      f16x4 v0 = *(const f16x4*)&h[(size_t)s0 * 64 + cl * 4];
      f16x4 v1 = *(const f16x4*)&h[(size_t)s1 * 64 + cl * 4];
#pragma unroll
      for (int i = 0; i < 4; i++) acc[i] += a0 * (float)v0[i] + a1 * (float)v1[i];
    }
    for (; j + 3 < jcap; j += 4) {
      int e0 = j + grp;
      int s0 = csr[e0];
      float a0 = __expf(elds[wid][e0 - jb] - m) * inv;
      f16x4 v0 = *(const f16x4*)&h[(size_t)s0 * 64 + cl * 4];
#pragma unroll
      for (int i = 0; i < 4; i++) acc[i] += a0 * (float)v0[i];
    }
    if (j + grp < jcap) {
      int e0 = j + grp;
      int s0 = csr[e0];
      float a0 = __expf(elds[wid][e0 - jb] - m) * inv;
      f16x4 v0 = *(const f16x4*)&h[(size_t)s0 * 64 + cl * 4];
#pragma unroll
      for (int i = 0; i < 4; i++) acc[i] += a0 * (float)v0[i];
    }
    for (int jj = jcap; jj < je; jj += 4) {
      int e0 = jj + grp;
      if (e0 < je) {
        int s0 = csr[e0];
        float a0 = __expf(leaky(a_s[s0] + ad) - m) * inv;
        f16x4 v0 = *(const f16x4*)&h[(size_t)s0 * 64 + cl * 4];
#pragma unroll
        for (int i = 0; i < 4; i++) acc[i] += a0 * (float)v0[i];
      }
    }
  }
#pragma unroll
  for (int i = 0; i < 4; i++) {
    acc[i] += __shfl_xor(acc[i], 16, 64);
    acc[i] += __shfl_xor(acc[i], 32, 64);
  }
  if (n < NNODES && l < 16) {
#pragma unroll
    for (int i = 0; i < 4; i++) sh[wid][cl * 4 + i] = elu(acc[i] + bias[cl * 4 + i]);
  }
  __syncthreads();
  float r = 0.f;
  if (l < 32 && n < NNODES) {
    r = b1[l];
#pragma unroll 8
    for (int k = 0; k < 64; k++) r += sh[wid][k] * w1[k * 32 + l];
    r = fmaxf(r, 0.f);
    r *= w2[l];
  }
  for (int mask = 16; mask >= 1; mask >>= 1) r += __shfl_xor(r, mask, 64);
  if (l == 0 && n < NNODES) out[n] = r + b2[0];
}

extern "C" void kernel_launch(void* const* d_in, const int* in_sizes, int n_in,
                              void* d_out, int out_size, void* d_ws, size_t ws_size,
                              hipStream_t stream) {
  const float* x    = (const float*)d_in[0];
  const int*   eidx = (const int*)d_in[1];
  const float* lin0 = (const float*)d_in[2];
  const float* as0  = (const float*)d_in[3];
  const float* ad0  = (const float*)d_in[4];
  const float* b0   = (const float*)d_in[5];
  const float* lin1 = (const float*)d_in[6];
  const float* as1  = (const float*)d_in[7];
  const float* ad1  = (const float*)d_in[8];
  const float* b1l  = (const float*)d_in[9];
  const float* lin2 = (const float*)d_in[10];
  const float* as2  = (const float*)d_in[11];
  const float* ad2  = (const float*)d_in[12];
  const float* b2l  = (const float*)d_in[13];
  const float* w1   = (const float*)d_in[14];
  const float* mb1  = (const float*)d_in[15];
  const float* w2   = (const float*)d_in[16];
  const float* mb2  = (const float*)d_in[17];
  float* outp = (float*)d_out;

  const int* srcA = eidx;
  const int* dstA = eidx + NEDGES;

  char* ws = (char*)d_ws;
  size_t o = 0;
  auto alloc = [&](size_t bytes) { size_t r = o; o += (bytes + 255) & ~255UL; return r; };
  _Float16* h16 = (_Float16*)(ws + alloc((size_t)NNODES * 256 * 2));
  _Float16* Ap  = (_Float16*)(ws + alloc((size_t)NNODES * 256 * 2));
  _Float16* wh0 = (_Float16*)(ws + alloc(128 * 256 * 2));
  _Float16* wh1 = (_Float16*)(ws + alloc(256 * 256 * 2));
  _Float16* wh2 = (_Float16*)(ws + alloc(256 * 64 * 2));
  float*  vas = (float*)(ws + alloc((size_t)NNODES * 4 * 4));
  float*  vad = (float*)(ws + alloc((size_t)NNODES * 4 * 4));
  int* row_start = (int*)(ws + alloc((NNODES + 1) * 4));
  int* fill      = (int*)(ws + alloc(NNODES * 4));
  int* csr       = (int*)(ws + alloc(NEDGES * 4));
  int* blocksum  = (int*)(ws + alloc(SCAN_NB * 4));
  int* blockoff  = (int*)(ws + alloc(SCAN_NB * 4));

  // prep: weight pack + fill zero (one dispatch), then x pack + dst histogram (one dispatch)
  k_prep_w3z<<<(NNODES + 255) / 256, 256, 0, stream>>>(lin0, lin1, lin2, wh0, wh1, wh2, fill);
  k_cvt_hist<<<(NEDGES + 255) / 256, 256, 0, stream>>>(x, Ap, NNODES * 4, dstA, fill, NEDGES);

  // CSR build
  k_scan1<<<SCAN_NB, 256, 0, stream>>>(fill, row_start, blocksum, NNODES);
  k_scan2<<<1, 128, 0, stream>>>(blocksum, blockoff, row_start, SCAN_NB, NNODES);
  k_scan3<<<SCAN_NB, 256, 0, stream>>>(row_start, blockoff, fill, NNODES);
  k_scatter<<<(NEDGES + 255) / 256, 256, 0, stream>>>(srcA, dstA, row_start, fill, csr, NEDGES);

  dim3 g44((NNODES + 63) / 64, 2);   // 4-head GEMMs: BM=64, BN=128
  dim3 g21((NNODES + 63) / 64, 1);   // 1-head GEMM:  BM=64, BN=64

  // ---- layer 0 (IN=128 -> 4x64, concat) ----
  k_gemm_mfma<128, 2, 4><<<g44, 256, 0, stream>>>((const ushort*)Ap, (const ushort*)wh0, as0, ad0, h16, vas, vad, NNODES, 256);
  k_gat4<<<5000, 256, 0, stream>>>(h16, vas, vad, row_start, csr, b0, Ap);

  // ---- layer 1 (256 -> 4x64, concat) ----
  k_gemm_mfma<256, 2, 4><<<g44, 256, 0, stream>>>((const ushort*)Ap, (const ushort*)wh1, as1, ad1, h16, vas, vad, NNODES, 256);
  k_gat4<<<5000, 256, 0, stream>>>(h16, vas, vad, row_start, csr, b1l, Ap);

  // ---- layer 2 (256 -> 64, 1 head, mean) + MLP ----
  k_gemm_mfma<256, 1, 1><<<g21, 256, 0, stream>>>((const ushort*)Ap, (const ushort*)wh2, as2, ad2, h16, vas, vad, NNODES, 64);
  k_gat1<<<5000, 256, 0, stream>>>(h16, vas, vad, row_start, csr, b2l, w1, mb1, w2, mb2, outp);
}